// Round 12
// baseline (199.095 us; speedup 1.0000x reference)
//
#include <hip/hip_runtime.h>

#define NN 16
#define BB 512
#define DD 256
#define RR (NN*BB)   // 8192

typedef __attribute__((ext_vector_type(8))) short v8s;
typedef __attribute__((ext_vector_type(4))) float v4f;
typedef __attribute__((ext_vector_type(16))) float v16f;
typedef __attribute__((ext_vector_type(4))) unsigned v4u;
typedef __attribute__((ext_vector_type(2))) unsigned v2u;

#define MFMA16(a,b,c) __builtin_amdgcn_mfma_f32_16x16x32_bf16((a),(b),(c),0,0,0)
#define MFMA32(a,b,c) __builtin_amdgcn_mfma_f32_32x32x16_bf16((a),(b),(c),0,0,0)

__device__ __forceinline__ unsigned short f2bf(float f){
  unsigned int x = __float_as_uint(f);
  x += 0x7fffu + ((x >> 16) & 1u);
  return (unsigned short)(x >> 16);
}
__device__ __forceinline__ float bf2f(unsigned short u){
  return __uint_as_float(((unsigned int)u) << 16);
}
// packed f32x2 -> bf16x2 (S0 -> low16, S1 -> high16), RTNE — same as f2bf
__device__ __forceinline__ unsigned cvt_pk(float lo, float hi){
  unsigned r;
  asm("v_cvt_pk_bf16_f32 %0, %1, %2" : "=v"(r) : "v"(lo), "v"(hi));
  return r;
}

// ---------- prep kernel (cast + weight transposes + concat, one launch) ----------
// iW2q/iW3q: 32x32x16 fragment-order:
//   chunk = (k>>4)*NT + (n>>5)   (NT = N/32); within chunk:
//   slot = (n&31) + ((k>>3)&1)*32 ; e = k&7  -> d = (chunk<<9)+(slot<<3)+e
//   => one wave B-frag load (lane slot, 16B) is 1KB contiguous.
__global__ __launch_bounds__(256) void k_prep(
    const float* __restrict__ objs,
    const float* __restrict__ tW1, const float* __restrict__ tW2, const float* __restrict__ tW3,
    const float* __restrict__ iW1, const float* __restrict__ iW2, const float* __restrict__ iW3,
    const float* __restrict__ tb1, const float* __restrict__ ib1,
    unsigned short* __restrict__ objsb,
    unsigned short* __restrict__ Wcat, unsigned short* __restrict__ tW2t, unsigned short* __restrict__ tW3t,
    unsigned short* __restrict__ iW2q, unsigned short* __restrict__ iW3q,
    float* __restrict__ bcat){
  int idx = blockIdx.x * 256 + threadIdx.x;
  if (idx < 524288){                                   // objs cast, float4 path
    float4 v = ((const float4*)objs)[idx];
    ushort4 o;
    o.x = f2bf(v.x); o.y = f2bf(v.y); o.z = f2bf(v.z); o.w = f2bf(v.w);
    ((ushort4*)objsb)[idx] = o;
    return;
  }
  idx -= 524288;
  if (idx < 131072){                                   // Wcat rows 0..511 <- tW1 [256][512]
    int n = idx >> 8, k = idx & 255;
    Wcat[idx] = f2bf(tW1[k * 512 + n]);
    return;
  }
  idx -= 131072;
  if (idx < 262144){                                   // tW2t [512][512]
    int n = idx >> 9, k = idx & 511;
    tW2t[idx] = f2bf(tW2[k * 512 + n]);
    return;
  }
  idx -= 262144;
  if (idx < 131072){                                   // tW3t [256][512] <- tW3 [512][256]
    int n = idx >> 9, k = idx & 511;
    tW3t[idx] = f2bf(tW3[k * 256 + n]);
    return;
  }
  idx -= 131072;
  if (idx < 262144){                                   // iW2q (32-frag-order) <- iW2 [512][512]
    int n = idx >> 9, k = idx & 511;
    int slot = (n & 31) + (((k >> 3) & 1) << 5);
    int d = ((((k >> 4) << 4) + (n >> 5)) << 9) + (slot << 3) + (k & 7);
    iW2q[d] = f2bf(iW2[k * 512 + n]);
    return;
  }
  idx -= 262144;
  if (idx < 131072){                                   // iW3q (32-frag-order) <- iW3 [512][256]
    int n = idx >> 9, k = idx & 511;
    int slot = (n & 31) + (((k >> 3) & 1) << 5);
    int d = ((((k >> 4) << 3) + (n >> 5)) << 9) + (slot << 3) + (k & 7);
    iW3q[d] = f2bf(iW3[k * 256 + n]);
    return;
  }
  idx -= 131072;
  if (idx < 262144){                                   // Wcat rows 512..1535 <- iW1 split
    int r = idx >> 8, k = idx & 255;
    float v = (r < 512) ? iW1[k * 512 + r] : iW1[(k + 256) * 512 + (r - 512)];
    Wcat[(512 << 8) + idx] = f2bf(v);
    return;
  }
  idx -= 262144;
  if (idx < 1536)
    bcat[idx] = (idx < 512) ? tb1[idx] : ((idx < 1024) ? 0.f : ib1[idx - 1024]);
}

// ---------- phase-A GEMM, 64x128 tile (kept for the T GEMM) ----------
template<int KD, bool OUTBF16, bool RELU, bool ADDX, bool SPLIT>
__global__ __launch_bounds__(256) void k_gemm(const unsigned short* __restrict__ A,
                                              const unsigned short* __restrict__ Wt,
                                              const float* __restrict__ bias,
                                              void* __restrict__ Cout,
                                              const float* __restrict__ extra,
                                              void* __restrict__ Cout2,
                                              int M, int Nn){
  __shared__ __align__(16) unsigned char sA[64 * 128];
  __shared__ __align__(16) unsigned char sB[128 * 128];
  const int m0 = blockIdx.x * 64;
  const int n0 = blockIdx.y * 128;
  const int t = threadIdx.x;
  const int w = t >> 6, l = t & 63;
  const int l15 = l & 15, lq = l >> 4;
  const int rowh = (w & 1) * 32, colh = (w >> 1) * 64;

  v4f c[2][4];
#pragma unroll
  for (int r = 0; r < 2; r++)
#pragma unroll
    for (int q = 0; q < 4; q++) c[r][q] = (v4f){0.f, 0.f, 0.f, 0.f};

  for (int kt = 0; kt < KD; kt += 64){
    __syncthreads();
    {
      const int row = t >> 2, cq = (t & 3) * 16;
      const unsigned short* src = A + (size_t)(m0 + row) * KD + kt + cq;
      v8s a0 = *(const v8s*)(src);
      v8s a1 = *(const v8s*)(src + 8);
      const unsigned sw = (unsigned)((row & 7) << 4);
      *(v8s*)(sA + ((unsigned)((row << 7) + (cq << 1)) ^ sw)) = a0;
      *(v8s*)(sA + ((unsigned)((row << 7) + (cq << 1) + 16) ^ sw)) = a1;
    }
    {
      const int n = t & 127, kq = (t >> 7) * 32;
      const unsigned short* src = Wt + (size_t)(n0 + n) * KD + kt + kq;
      const unsigned base = (unsigned)((n << 7) + (kq << 1));
      const unsigned sw = (unsigned)((n & 7) << 4);
#pragma unroll
      for (int q = 0; q < 4; q++){
        v8s v = *(const v8s*)(src + q * 8);
        *(v8s*)(sB + ((base + q * 16) ^ sw)) = v;
      }
    }
    __syncthreads();
#pragma unroll
    for (int kb = 0; kb < 64; kb += 32){
      v8s af[2], bfr[4];
#pragma unroll
      for (int r = 0; r < 2; r++){
        const int row = rowh + r * 16 + l15;
        af[r] = *(const v8s*)(sA + ((unsigned)((row << 7) + ((kb + (lq << 3)) << 1)) ^ (unsigned)((row & 7) << 4)));
      }
#pragma unroll
      for (int q = 0; q < 4; q++){
        const int n = colh + q * 16 + l15;
        bfr[q] = *(const v8s*)(sB + ((unsigned)((n << 7) + ((kb + (lq << 3)) << 1)) ^ (unsigned)((n & 7) << 4)));
      }
#pragma unroll
      for (int r = 0; r < 2; r++)
#pragma unroll
        for (int q = 0; q < 4; q++)
          c[r][q] = MFMA16(af[r], bfr[q], c[r][q]);
    }
  }
#pragma unroll
  for (int r = 0; r < 2; r++){
#pragma unroll
    for (int q = 0; q < 4; q++){
      const int col = n0 + colh + q * 16 + l15;
      const float bv = bias ? bias[col] : 0.0f;
#pragma unroll
      for (int e = 0; e < 4; e++){
        const int row = m0 + rowh + r * 16 + (lq << 2) + e;
        float v = c[r][q][e] + bv;
        if (SPLIT){
          if (col < 512){
            ((unsigned short*)Cout)[(size_t)row * 512 + col] = f2bf(fmaxf(v, 0.0f));
          } else {
            ((unsigned short*)Cout2)[(size_t)row * 1024 + (col - 512)] = f2bf(v);
          }
        } else {
          if (RELU) v = fmaxf(v, 0.0f);
          if (ADDX) v += extra[(size_t)row * Nn + col];
          if (OUTBF16) ((unsigned short*)Cout)[(size_t)row * Nn + col] = f2bf(v);
          else         ((float*)Cout)[(size_t)row * Nn + col] = v;
        }
      }
    }
  }
}

// ---------- phase-A GEMM, 128x128 tile (merged H1/UV + H2) ----------
template<int KD, bool OUTBF16, bool RELU, bool SPLIT>
__global__ __launch_bounds__(256) void k_gemmB(const unsigned short* __restrict__ A,
                                               const unsigned short* __restrict__ Wt,
                                               const float* __restrict__ bias,
                                               void* __restrict__ Cout,
                                               void* __restrict__ Cout2){
  __shared__ __align__(16) unsigned char sA[128 * 128];  // [128 m][64 k]
  __shared__ __align__(16) unsigned char sB[128 * 128];  // [128 n][64 k]
  const int m0 = blockIdx.x * 128;
  const int n0 = blockIdx.y * 128;
  const int t = threadIdx.x;
  const int w = t >> 6, l = t & 63, l15 = l & 15, lq = l >> 4;
  const int wr = (w >> 1) * 64, wc = (w & 1) * 64;

  v4f c[4][4];
#pragma unroll
  for (int r = 0; r < 4; r++)
#pragma unroll
    for (int q = 0; q < 4; q++) c[r][q] = (v4f){0.f, 0.f, 0.f, 0.f};

  const int sr = t >> 1, sk = (t & 1) * 32;          // 2 threads/row, 32 k each
  const unsigned sbase = (unsigned)((sr << 7) + (sk << 1));
  const unsigned ssw = (unsigned)((sr & 7) << 4);

  for (int kt = 0; kt < KD; kt += 64){
    __syncthreads();
    { // stage A
      const unsigned short* src = A + (size_t)(m0 + sr) * KD + kt + sk;
      v8s a0 = *(const v8s*)(src);
      v8s a1 = *(const v8s*)(src + 8);
      v8s a2 = *(const v8s*)(src + 16);
      v8s a3 = *(const v8s*)(src + 24);
      *(v8s*)(sA + ((sbase +  0) ^ ssw)) = a0;
      *(v8s*)(sA + ((sbase + 16) ^ ssw)) = a1;
      *(v8s*)(sA + ((sbase + 32) ^ ssw)) = a2;
      *(v8s*)(sA + ((sbase + 48) ^ ssw)) = a3;
    }
    { // stage B
      const unsigned short* src = Wt + (size_t)(n0 + sr) * KD + kt + sk;
      v8s b0 = *(const v8s*)(src);
      v8s b1 = *(const v8s*)(src + 8);
      v8s b2 = *(const v8s*)(src + 16);
      v8s b3 = *(const v8s*)(src + 24);
      *(v8s*)(sB + ((sbase +  0) ^ ssw)) = b0;
      *(v8s*)(sB + ((sbase + 16) ^ ssw)) = b1;
      *(v8s*)(sB + ((sbase + 32) ^ ssw)) = b2;
      *(v8s*)(sB + ((sbase + 48) ^ ssw)) = b3;
    }
    __syncthreads();
#pragma unroll
    for (int kb = 0; kb < 64; kb += 32){
      v8s af[4], bfr[4];
#pragma unroll
      for (int r = 0; r < 4; r++){
        const int row = wr + r * 16 + l15;
        af[r] = *(const v8s*)(sA + ((unsigned)((row << 7) + ((kb + (lq << 3)) << 1)) ^ (unsigned)((row & 7) << 4)));
      }
#pragma unroll
      for (int q = 0; q < 4; q++){
        const int n = wc + q * 16 + l15;
        bfr[q] = *(const v8s*)(sB + ((unsigned)((n << 7) + ((kb + (lq << 3)) << 1)) ^ (unsigned)((n & 7) << 4)));
      }
#pragma unroll
      for (int r = 0; r < 4; r++)
#pragma unroll
        for (int q = 0; q < 4; q++)
          c[r][q] = MFMA16(af[r], bfr[q], c[r][q]);
    }
  }
#pragma unroll
  for (int r = 0; r < 4; r++){
#pragma unroll
    for (int q = 0; q < 4; q++){
      const int col = n0 + wc + q * 16 + l15;
      const float bv = bias ? bias[col] : 0.0f;
#pragma unroll
      for (int e = 0; e < 4; e++){
        const int row = m0 + wr + r * 16 + (lq << 2) + e;
        float v = c[r][q][e] + bv;
        if (SPLIT){
          if (col < 512){
            ((unsigned short*)Cout)[(size_t)row * 512 + col] = f2bf(fmaxf(v, 0.0f));
          } else {
            ((unsigned short*)Cout2)[(size_t)row * 1024 + (col - 512)] = f2bf(v);
          }
        } else {
          if (RELU) v = fmaxf(v, 0.0f);
          if (OUTBF16) ((unsigned short*)Cout)[(size_t)row * 512 + col] = f2bf(v);
          else         ((float*)Cout)[(size_t)row * 512 + col] = v;
        }
      }
    }
  }
}

// ---------- fused pair kernel — 32x32x16 MFMA version ----------
// One WG = one (i,j) pair x 128 batch rows. 512 threads (8 waves), 160 KB LDS.
// Quarter-outer XCD mapping; dbuf sA1, 1 barrier/K-step. MFMA = 32x32x16:
// half the MFMA instructions, 21% higher pipe rate, a1f live regs 32->16.
// C/D layout (verified): col=lane&31, row=(reg&3)+8*(reg>>2)+4*(lane>>5).
// A/B inputs packed with row/col=lane&31, k=(lane>>5)*8+e — any consistent
// k-permutation cancels between the two operands.
__global__ __launch_bounds__(512, 2) void k_pair2(
    const unsigned short* __restrict__ UV,   // [8192][1024] bf16: U' | V'+ib1
    const unsigned short* __restrict__ W2q,  // 32-frag-order [32 k16][16 nt][512]
    const unsigned short* __restrict__ W3q,  // 32-frag-order [32 k16][8 nt][512]
    const float* __restrict__ b2,
    const float* __restrict__ b3,
    unsigned short* __restrict__ P){         // [240][131072] bf16 partials (permuted)
  __shared__ __align__(16) unsigned char sA1[2][128 * 128]; // 2 x 16 KB [128 m][64 k]
  __shared__ __align__(16) unsigned char sA2[128 * 1024];   // 128 KB [128 m][512 k]

  const int bid = blockIdx.x;
  const int xcd = bid & 7;
  const int cc  = bid >> 3;              // 0..119 within XCD
  const int q4  = cc / 30;               // quarter OUTER
  const int pl  = cc - q4 * 30;
  const int p   = xcd * 30 + pl;         // pair 0..239 (i-major per XCD)
  const int i   = p / 15;
  const int rj  = p - i * 15;
  const int j   = rj + (rj >= i ? 1 : 0);
  const int b0  = q4 * 128;

  const int t = threadIdx.x;
  const int w = t >> 6, l = t & 63;
  const int la = l & 31, h = l >> 5;
  const int n0w = w * 64;

  const unsigned short* Up = UV + (((size_t)(i * BB + b0)) << 10);
  const unsigned short* Vp = UV + (((size_t)(j * BB + b0)) << 10) + 512;

  const int sr = t >> 2, sk = (t & 3) << 4;
  const size_t srow = (size_t)sr << 10;
  const unsigned sbase = (unsigned)((sr << 7) + (sk << 1));
  const unsigned ssw = (unsigned)((sr & 7) << 4);

  v8s u0, u1, v0, v1;

  auto ld_uv = [&](int kt){
    u0 = *(const v8s*)(Up + srow + kt + sk);
    u1 = *(const v8s*)(Up + srow + kt + sk + 8);
    v0 = *(const v8s*)(Vp + srow + kt + sk);
    v1 = *(const v8s*)(Vp + srow + kt + sk + 8);
  };
  auto build_a1 = [&](unsigned char* dst){
    float f0[8], f1[8];
#pragma unroll
    for (int e = 0; e < 8; e++){
      f0[e] = fmaxf(bf2f((unsigned short)u0[e]) + bf2f((unsigned short)v0[e]), 0.f);
      f1[e] = fmaxf(bf2f((unsigned short)u1[e]) + bf2f((unsigned short)v1[e]), 0.f);
    }
    v4u q0, q1;
    q0.x = cvt_pk(f0[0], f0[1]); q0.y = cvt_pk(f0[2], f0[3]);
    q0.z = cvt_pk(f0[4], f0[5]); q0.w = cvt_pk(f0[6], f0[7]);
    q1.x = cvt_pk(f1[0], f1[1]); q1.y = cvt_pk(f1[2], f1[3]);
    q1.z = cvt_pk(f1[4], f1[5]); q1.w = cvt_pk(f1[6], f1[7]);
    *(v4u*)(dst + (sbase ^ ssw)) = q0;
    *(v4u*)(dst + ((sbase + 16) ^ ssw)) = q1;
  };

  // GEMM2: c2[nt][mt], nt: n-tile 32 within wave's 64 cols, mt: m-tile 32 of 128.
  // swapped mfma(w2, a1): D col(lane&31)=m, D row(regs)=n.
  v16f c2[2][4];
#pragma unroll
  for (int nt = 0; nt < 2; nt++)
#pragma unroll
    for (int mt = 0; mt < 4; mt++)
#pragma unroll
      for (int e = 0; e < 16; e++) c2[nt][mt][e] = 0.f;

  // prologue: A1(0) into buf0; prime regs for A1(1)
  ld_uv(0);
  build_a1(&sA1[0][0]);
  ld_uv(64);

#pragma unroll
  for (int s = 0; s < 8; ++s){
    __syncthreads();                       // A1(s) visible; buf[(s+1)&1] free
    if (s < 7) build_a1(&sA1[(s + 1) & 1][0]);
    if (s < 6) ld_uv((s + 2) * 64);
    const unsigned char* bufc = &sA1[s & 1][0];
#pragma unroll
    for (int kk = 0; kk < 4; kk++){
      const int K16 = s * 4 + kk;
      v8s w2f[2], a1f[4];
#pragma unroll
      for (int nt = 0; nt < 2; nt++)
        w2f[nt] = *(const v8s*)(W2q + (((size_t)((K16 << 4) + (w * 2 + nt))) << 9) + (l << 3));
#pragma unroll
      for (int mt = 0; mt < 4; mt++){
        const int row = mt * 32 + la;
        a1f[mt] = *(const v8s*)(bufc + ((unsigned)((row << 7) + kk * 32 + h * 16) ^ (unsigned)((row & 7) << 4)));
      }
      __builtin_amdgcn_s_setprio(1);
#pragma unroll
      for (int nt = 0; nt < 2; nt++)
#pragma unroll
        for (int mt = 0; mt < 4; mt++)
          c2[nt][mt] = MFMA32(w2f[nt], a1f[mt], c2[nt][mt]);
      __builtin_amdgcn_s_setprio(0);
    }
  }

  // A2 = relu(c2 + b2) -> sA2 [m][k=n] ; lane's 16 regs span n in 4-runs
  // n = n0w + nt*32 + 8q + 4h + r  (reg = 4q+r), m = mt*32 + la.
#pragma unroll
  for (int nt = 0; nt < 2; nt++){
#pragma unroll
    for (int q = 0; q < 4; q++){
      const int nb = n0w + nt * 32 + 8 * q + 4 * h;
      const float4 bb = *(const float4*)(b2 + nb);
#pragma unroll
      for (int mt = 0; mt < 4; mt++){
        const int row = mt * 32 + la;
        uint2 u;
        u.x = cvt_pk(fmaxf(c2[nt][mt][4 * q + 0] + bb.x, 0.f), fmaxf(c2[nt][mt][4 * q + 1] + bb.y, 0.f));
        u.y = cvt_pk(fmaxf(c2[nt][mt][4 * q + 2] + bb.z, 0.f), fmaxf(c2[nt][mt][4 * q + 3] + bb.w, 0.f));
        *(uint2*)(sA2 + ((unsigned)((row << 10) + (nb << 1)) ^ (unsigned)((row & 7) << 4))) = u;
      }
    }
  }
  __syncthreads();

  // GEMM3: barrier-free. wave (wm, wn): rows wm*64 (2 mt-tiles), cols wn*64 (2 nt).
  // un-swapped mfma(a2, w3): D col(lane&31)=n, D row(regs)=m.
  const int wm = w & 1, wn = w >> 1;
  v16f c3[2][2];
#pragma unroll
  for (int mt = 0; mt < 2; mt++)
#pragma unroll
    for (int nt = 0; nt < 2; nt++)
#pragma unroll
      for (int e = 0; e < 16; e++) c3[mt][nt][e] = 0.f;

#pragma unroll 4
  for (int kk = 0; kk < 32; kk++){
    v8s a2f[2], w3f[2];
#pragma unroll
    for (int nt = 0; nt < 2; nt++)
      w3f[nt] = *(const v8s*)(W3q + (((size_t)((kk << 3) + (wn * 2 + nt))) << 9) + (l << 3));
#pragma unroll
    for (int mt = 0; mt < 2; mt++){
      const int row = wm * 64 + mt * 32 + la;
      a2f[mt] = *(const v8s*)(sA2 + ((unsigned)((row << 10) + ((kk * 16 + h * 8) << 1)) ^ (unsigned)((row & 7) << 4)));
    }
    __builtin_amdgcn_s_setprio(1);
#pragma unroll
    for (int mt = 0; mt < 2; mt++)
#pragma unroll
      for (int nt = 0; nt < 2; nt++)
        c3[mt][nt] = MFMA32(a2f[mt], w3f[nt], c3[mt][nt]);
    __builtin_amdgcn_s_setprio(0);
  }

  // epilogue: relu(c3+b3) -> permuted P slab, packed nt stores (512B/instr).
  // P layout (uint2 units): addr2 = BB*64 + la*2 + h,
  //   BB = rg*32 + ng*4 + q ; rg = (q4*2+wm)*2+mt (32-row group), ng = wn*2+nt.
  //   uint2 holds m-rows rg*32 + 8q + 4h + {0..3}, col n = ng*32 + la.
  {
    const float b3v0 = b3[wn * 64 + la];
    const float b3v1 = b3[wn * 64 + 32 + la];
    unsigned short* pb = P + ((size_t)p << 17) + (la << 3) + (h << 2);
#pragma unroll
    for (int mt = 0; mt < 2; mt++){
      const int rg = (q4 * 2 + wm) * 2 + mt;
#pragma unroll
      for (int nt = 0; nt < 2; nt++){
        const int ng = wn * 2 + nt;
        const float bv = nt ? b3v1 : b3v0;
#pragma unroll
        for (int q = 0; q < 4; q++){
          const int BBi = (rg << 5) + (ng << 2) + q;
          v2u u;
          u.x = cvt_pk(fmaxf(c3[mt][nt][4 * q + 0] + bv, 0.f), fmaxf(c3[mt][nt][4 * q + 1] + bv, 0.f));
          u.y = cvt_pk(fmaxf(c3[mt][nt][4 * q + 2] + bv, 0.f), fmaxf(c3[mt][nt][4 * q + 3] + bv, 0.f));
          __builtin_nontemporal_store(u, (v2u*)(pb + ((size_t)BBi << 8)));
        }
      }
    }
  }
}

// ---------- slab reduction: out += sum_{15 slabs of i} P (decode permuted) ----------
__global__ __launch_bounds__(256) void k_reduce(const unsigned short* __restrict__ P,
                                                float* __restrict__ out){
  int idx = blockIdx.x * 256 + threadIdx.x;     // 262144 threads, one v8s each
  const int i  = idx >> 14;
  const int g8 = idx & 16383;                   // v8s unit within slab
  const unsigned short* pb = P + (((size_t)(i * 15)) << 17) + ((size_t)g8 << 3);
  float s[8] = {0.f,0.f,0.f,0.f,0.f,0.f,0.f,0.f};
#pragma unroll
  for (int sl = 0; sl < 15; sl++){
    v8s v = __builtin_nontemporal_load((const v8s*)(pb + ((size_t)sl << 17)));
#pragma unroll
    for (int e = 0; e < 8; e++) s[e] += bf2f((unsigned short)v[e]);
  }
  // decode: g8 = BB*32 + la ; BB = rg*32 + ng*4 + q ; elem e -> m-offset e
  const int la = g8 & 31, B = g8 >> 5;
  const int q = B & 3, ng = (B >> 2) & 7, rg = B >> 5;   // rg 0..15
  const int rowb = (i << 9) + rg * 32 + 8 * q;
  const int col  = ng * 32 + la;
  float* ob = out + ((size_t)rowb << 8) + col;
#pragma unroll
  for (int e = 0; e < 8; e++)
    ob[(size_t)(e << 8)] += s[e];
}

// ---------- host ----------

extern "C" void kernel_launch(void* const* d_in, const int* in_sizes, int n_in,
                              void* d_out, int out_size, void* d_ws, size_t ws_size,
                              hipStream_t stream){
  const float* objs = (const float*)d_in[0];
  const float* tW1  = (const float*)d_in[1];
  const float* tb1  = (const float*)d_in[2];
  const float* tW2  = (const float*)d_in[3];
  const float* tb2  = (const float*)d_in[4];
  const float* tW3  = (const float*)d_in[5];
  const float* tb3  = (const float*)d_in[6];
  const float* iW1  = (const float*)d_in[7];
  const float* ib1  = (const float*)d_in[8];
  const float* iW2  = (const float*)d_in[9];
  const float* ib2  = (const float*)d_in[10];
  const float* iW3  = (const float*)d_in[11];
  const float* ib3  = (const float*)d_in[12];

  char* ws = (char*)d_ws;
  size_t off = 0;
  unsigned short* objsb = (unsigned short*)(ws + off); off += (size_t)RR * DD * 2;        // 4 MB
  unsigned short* H1    = (unsigned short*)(ws + off); off += (size_t)RR * 512 * 2;       // 8 MB
  unsigned short* H2    = (unsigned short*)(ws + off); off += (size_t)RR * 512 * 2;       // 8 MB
  unsigned short* UVb   = (unsigned short*)(ws + off); off += (size_t)RR * 1024 * 2;      // 16 MB
  unsigned short* Wcat  = (unsigned short*)(ws + off); off += 1536 * 256 * 2;
  unsigned short* tW2t  = (unsigned short*)(ws + off); off += 512 * 512 * 2;
  unsigned short* tW3t  = (unsigned short*)(ws + off); off += 256 * 512 * 2;
  unsigned short* iW2q  = (unsigned short*)(ws + off); off += 512 * 512 * 2;
  unsigned short* iW3q  = (unsigned short*)(ws + off); off += 256 * 512 * 2;
  float*          bcat  = (float*)(ws + off);          off += 1536 * 4;
  unsigned short* P     = (unsigned short*)(ws + off); off += (size_t)240 * 512 * 256 * 2; // 60 MB
  (void)ws_size; (void)in_sizes; (void)n_in; (void)out_size;

  // prep (cast + transposes, one launch)
  k_prep<<<dim3(6662), dim3(256), 0, stream>>>(objs, tW1, tW2, tW3, iW1, iW2, iW3, tb1, ib1,
                                               objsb, Wcat, tW2t, tW3t, iW2q, iW3q, bcat);

  // merged H1 + UV GEMM (128x128 tiles, split epilogue)
  k_gemmB<256, true, false, true ><<<dim3(RR / 128, 12), dim3(256), 0, stream>>>(
      objsb, Wcat, bcat, H1, UVb);
  // H2 = relu(H1@tW2+tb2) (128x128 tiles)
  k_gemmB<512, true, true,  false><<<dim3(RR / 128, 4), dim3(256), 0, stream>>>(
      H1, tW2t, tb2, H2, nullptr);
  // T path: out = relu(H2@tW3+tb3) + objs (64x128 tiles, Nn=256)
  k_gemm<512, false, true, true, false><<<dim3(RR / 64, 2), dim3(256), 0, stream>>>(
      H2, tW3t, tb3, d_out, objs, nullptr, RR, DD);

  // fused pair interaction -> bf16 permuted partial slabs (nt stores)
  k_pair2<<<dim3(960), dim3(512), 0, stream>>>(UVb, iW2q, iW3q, ib2, ib3, P);

  // out += sum of 15 slabs per i
  k_reduce<<<dim3(1024), dim3(256), 0, stream>>>(P, (float*)d_out);
}

// Round 13
// 179.898 us; speedup vs baseline: 1.1067x; 1.1067x over previous
//
#include <hip/hip_runtime.h>

#define NN 16
#define BB 512
#define DD 256
#define RR (NN*BB)   // 8192

typedef __attribute__((ext_vector_type(8))) short v8s;
typedef __attribute__((ext_vector_type(4))) float v4f;
typedef __attribute__((ext_vector_type(16))) float v16f;
typedef __attribute__((ext_vector_type(4))) unsigned v4u;
typedef __attribute__((ext_vector_type(2))) unsigned v2u;

#define MFMA16(a,b,c) __builtin_amdgcn_mfma_f32_16x16x32_bf16((a),(b),(c),0,0,0)
#define MFMA32(a,b,c) __builtin_amdgcn_mfma_f32_32x32x16_bf16((a),(b),(c),0,0,0)

__device__ __forceinline__ unsigned short f2bf(float f){
  unsigned int x = __float_as_uint(f);
  x += 0x7fffu + ((x >> 16) & 1u);
  return (unsigned short)(x >> 16);
}
__device__ __forceinline__ float bf2f(unsigned short u){
  return __uint_as_float(((unsigned int)u) << 16);
}
// packed f32x2 -> bf16x2 (S0 -> low16, S1 -> high16), RTNE — same as f2bf
__device__ __forceinline__ unsigned cvt_pk(float lo, float hi){
  unsigned r;
  asm("v_cvt_pk_bf16_f32 %0, %1, %2" : "=v"(r) : "v"(lo), "v"(hi));
  return r;
}

// ---------- prep kernel (cast + weight transposes + concat, one launch) ----------
// iW2q/iW3q: 32x32x16 fragment-order:
//   chunk = (k>>4)*NT + (n>>5)   (NT = N/32); within chunk:
//   slot = (n&31) + ((k>>3)&1)*32 ; e = k&7  -> d = (chunk<<9)+(slot<<3)+e
__global__ __launch_bounds__(256) void k_prep(
    const float* __restrict__ objs,
    const float* __restrict__ tW1, const float* __restrict__ tW2, const float* __restrict__ tW3,
    const float* __restrict__ iW1, const float* __restrict__ iW2, const float* __restrict__ iW3,
    const float* __restrict__ tb1, const float* __restrict__ ib1,
    unsigned short* __restrict__ objsb,
    unsigned short* __restrict__ Wcat, unsigned short* __restrict__ tW2t, unsigned short* __restrict__ tW3t,
    unsigned short* __restrict__ iW2q, unsigned short* __restrict__ iW3q,
    float* __restrict__ bcat){
  int idx = blockIdx.x * 256 + threadIdx.x;
  if (idx < 524288){                                   // objs cast, float4 path
    float4 v = ((const float4*)objs)[idx];
    ushort4 o;
    o.x = f2bf(v.x); o.y = f2bf(v.y); o.z = f2bf(v.z); o.w = f2bf(v.w);
    ((ushort4*)objsb)[idx] = o;
    return;
  }
  idx -= 524288;
  if (idx < 131072){                                   // Wcat rows 0..511 <- tW1 [256][512]
    int n = idx >> 8, k = idx & 255;
    Wcat[idx] = f2bf(tW1[k * 512 + n]);
    return;
  }
  idx -= 131072;
  if (idx < 262144){                                   // tW2t [512][512]
    int n = idx >> 9, k = idx & 511;
    tW2t[idx] = f2bf(tW2[k * 512 + n]);
    return;
  }
  idx -= 262144;
  if (idx < 131072){                                   // tW3t [256][512] <- tW3 [512][256]
    int n = idx >> 9, k = idx & 511;
    tW3t[idx] = f2bf(tW3[k * 256 + n]);
    return;
  }
  idx -= 131072;
  if (idx < 262144){                                   // iW2q (32-frag-order) <- iW2 [512][512]
    int n = idx >> 9, k = idx & 511;
    int slot = (n & 31) + (((k >> 3) & 1) << 5);
    int d = ((((k >> 4) << 4) + (n >> 5)) << 9) + (slot << 3) + (k & 7);
    iW2q[d] = f2bf(iW2[k * 512 + n]);
    return;
  }
  idx -= 262144;
  if (idx < 131072){                                   // iW3q (32-frag-order) <- iW3 [512][256]
    int n = idx >> 9, k = idx & 511;
    int slot = (n & 31) + (((k >> 3) & 1) << 5);
    int d = ((((k >> 4) << 3) + (n >> 5)) << 9) + (slot << 3) + (k & 7);
    iW3q[d] = f2bf(iW3[k * 256 + n]);
    return;
  }
  idx -= 131072;
  if (idx < 262144){                                   // Wcat rows 512..1535 <- iW1 split
    int r = idx >> 8, k = idx & 255;
    float v = (r < 512) ? iW1[k * 512 + r] : iW1[(k + 256) * 512 + (r - 512)];
    Wcat[(512 << 8) + idx] = f2bf(v);
    return;
  }
  idx -= 262144;
  if (idx < 1536)
    bcat[idx] = (idx < 512) ? tb1[idx] : ((idx < 1024) ? 0.f : ib1[idx - 1024]);
}

// ---------- phase-A GEMM, 64x128 tile (kept for the T GEMM) ----------
template<int KD, bool OUTBF16, bool RELU, bool ADDX, bool SPLIT>
__global__ __launch_bounds__(256) void k_gemm(const unsigned short* __restrict__ A,
                                              const unsigned short* __restrict__ Wt,
                                              const float* __restrict__ bias,
                                              void* __restrict__ Cout,
                                              const float* __restrict__ extra,
                                              void* __restrict__ Cout2,
                                              int M, int Nn){
  __shared__ __align__(16) unsigned char sA[64 * 128];
  __shared__ __align__(16) unsigned char sB[128 * 128];
  const int m0 = blockIdx.x * 64;
  const int n0 = blockIdx.y * 128;
  const int t = threadIdx.x;
  const int w = t >> 6, l = t & 63;
  const int l15 = l & 15, lq = l >> 4;
  const int rowh = (w & 1) * 32, colh = (w >> 1) * 64;

  v4f c[2][4];
#pragma unroll
  for (int r = 0; r < 2; r++)
#pragma unroll
    for (int q = 0; q < 4; q++) c[r][q] = (v4f){0.f, 0.f, 0.f, 0.f};

  for (int kt = 0; kt < KD; kt += 64){
    __syncthreads();
    {
      const int row = t >> 2, cq = (t & 3) * 16;
      const unsigned short* src = A + (size_t)(m0 + row) * KD + kt + cq;
      v8s a0 = *(const v8s*)(src);
      v8s a1 = *(const v8s*)(src + 8);
      const unsigned sw = (unsigned)((row & 7) << 4);
      *(v8s*)(sA + ((unsigned)((row << 7) + (cq << 1)) ^ sw)) = a0;
      *(v8s*)(sA + ((unsigned)((row << 7) + (cq << 1) + 16) ^ sw)) = a1;
    }
    {
      const int n = t & 127, kq = (t >> 7) * 32;
      const unsigned short* src = Wt + (size_t)(n0 + n) * KD + kt + kq;
      const unsigned base = (unsigned)((n << 7) + (kq << 1));
      const unsigned sw = (unsigned)((n & 7) << 4);
#pragma unroll
      for (int q = 0; q < 4; q++){
        v8s v = *(const v8s*)(src + q * 8);
        *(v8s*)(sB + ((base + q * 16) ^ sw)) = v;
      }
    }
    __syncthreads();
#pragma unroll
    for (int kb = 0; kb < 64; kb += 32){
      v8s af[2], bfr[4];
#pragma unroll
      for (int r = 0; r < 2; r++){
        const int row = rowh + r * 16 + l15;
        af[r] = *(const v8s*)(sA + ((unsigned)((row << 7) + ((kb + (lq << 3)) << 1)) ^ (unsigned)((row & 7) << 4)));
      }
#pragma unroll
      for (int q = 0; q < 4; q++){
        const int n = colh + q * 16 + l15;
        bfr[q] = *(const v8s*)(sB + ((unsigned)((n << 7) + ((kb + (lq << 3)) << 1)) ^ (unsigned)((n & 7) << 4)));
      }
#pragma unroll
      for (int r = 0; r < 2; r++)
#pragma unroll
        for (int q = 0; q < 4; q++)
          c[r][q] = MFMA16(af[r], bfr[q], c[r][q]);
    }
  }
#pragma unroll
  for (int r = 0; r < 2; r++){
#pragma unroll
    for (int q = 0; q < 4; q++){
      const int col = n0 + colh + q * 16 + l15;
      const float bv = bias ? bias[col] : 0.0f;
#pragma unroll
      for (int e = 0; e < 4; e++){
        const int row = m0 + rowh + r * 16 + (lq << 2) + e;
        float v = c[r][q][e] + bv;
        if (SPLIT){
          if (col < 512){
            ((unsigned short*)Cout)[(size_t)row * 512 + col] = f2bf(fmaxf(v, 0.0f));
          } else {
            ((unsigned short*)Cout2)[(size_t)row * 1024 + (col - 512)] = f2bf(v);
          }
        } else {
          if (RELU) v = fmaxf(v, 0.0f);
          if (ADDX) v += extra[(size_t)row * Nn + col];
          if (OUTBF16) ((unsigned short*)Cout)[(size_t)row * Nn + col] = f2bf(v);
          else         ((float*)Cout)[(size_t)row * Nn + col] = v;
        }
      }
    }
  }
}

// ---------- phase-A GEMM, 128x128 tile (merged H1/UV + H2) ----------
template<int KD, bool OUTBF16, bool RELU, bool SPLIT>
__global__ __launch_bounds__(256) void k_gemmB(const unsigned short* __restrict__ A,
                                               const unsigned short* __restrict__ Wt,
                                               const float* __restrict__ bias,
                                               void* __restrict__ Cout,
                                               void* __restrict__ Cout2){
  __shared__ __align__(16) unsigned char sA[128 * 128];  // [128 m][64 k]
  __shared__ __align__(16) unsigned char sB[128 * 128];  // [128 n][64 k]
  const int m0 = blockIdx.x * 128;
  const int n0 = blockIdx.y * 128;
  const int t = threadIdx.x;
  const int w = t >> 6, l = t & 63, l15 = l & 15, lq = l >> 4;
  const int wr = (w >> 1) * 64, wc = (w & 1) * 64;

  v4f c[4][4];
#pragma unroll
  for (int r = 0; r < 4; r++)
#pragma unroll
    for (int q = 0; q < 4; q++) c[r][q] = (v4f){0.f, 0.f, 0.f, 0.f};

  const int sr = t >> 1, sk = (t & 1) * 32;          // 2 threads/row, 32 k each
  const unsigned sbase = (unsigned)((sr << 7) + (sk << 1));
  const unsigned ssw = (unsigned)((sr & 7) << 4);

  for (int kt = 0; kt < KD; kt += 64){
    __syncthreads();
    { // stage A
      const unsigned short* src = A + (size_t)(m0 + sr) * KD + kt + sk;
      v8s a0 = *(const v8s*)(src);
      v8s a1 = *(const v8s*)(src + 8);
      v8s a2 = *(const v8s*)(src + 16);
      v8s a3 = *(const v8s*)(src + 24);
      *(v8s*)(sA + ((sbase +  0) ^ ssw)) = a0;
      *(v8s*)(sA + ((sbase + 16) ^ ssw)) = a1;
      *(v8s*)(sA + ((sbase + 32) ^ ssw)) = a2;
      *(v8s*)(sA + ((sbase + 48) ^ ssw)) = a3;
    }
    { // stage B
      const unsigned short* src = Wt + (size_t)(n0 + sr) * KD + kt + sk;
      v8s b0 = *(const v8s*)(src);
      v8s b1 = *(const v8s*)(src + 8);
      v8s b2 = *(const v8s*)(src + 16);
      v8s b3 = *(const v8s*)(src + 24);
      *(v8s*)(sB + ((sbase +  0) ^ ssw)) = b0;
      *(v8s*)(sB + ((sbase + 16) ^ ssw)) = b1;
      *(v8s*)(sB + ((sbase + 32) ^ ssw)) = b2;
      *(v8s*)(sB + ((sbase + 48) ^ ssw)) = b3;
    }
    __syncthreads();
#pragma unroll
    for (int kb = 0; kb < 64; kb += 32){
      v8s af[4], bfr[4];
#pragma unroll
      for (int r = 0; r < 4; r++){
        const int row = wr + r * 16 + l15;
        af[r] = *(const v8s*)(sA + ((unsigned)((row << 7) + ((kb + (lq << 3)) << 1)) ^ (unsigned)((row & 7) << 4)));
      }
#pragma unroll
      for (int q = 0; q < 4; q++){
        const int n = wc + q * 16 + l15;
        bfr[q] = *(const v8s*)(sB + ((unsigned)((n << 7) + ((kb + (lq << 3)) << 1)) ^ (unsigned)((n & 7) << 4)));
      }
#pragma unroll
      for (int r = 0; r < 4; r++)
#pragma unroll
        for (int q = 0; q < 4; q++)
          c[r][q] = MFMA16(af[r], bfr[q], c[r][q]);
    }
  }
#pragma unroll
  for (int r = 0; r < 4; r++){
#pragma unroll
    for (int q = 0; q < 4; q++){
      const int col = n0 + wc + q * 16 + l15;
      const float bv = bias ? bias[col] : 0.0f;
#pragma unroll
      for (int e = 0; e < 4; e++){
        const int row = m0 + wr + r * 16 + (lq << 2) + e;
        float v = c[r][q][e] + bv;
        if (SPLIT){
          if (col < 512){
            ((unsigned short*)Cout)[(size_t)row * 512 + col] = f2bf(fmaxf(v, 0.0f));
          } else {
            ((unsigned short*)Cout2)[(size_t)row * 1024 + (col - 512)] = f2bf(v);
          }
        } else {
          if (RELU) v = fmaxf(v, 0.0f);
          if (OUTBF16) ((unsigned short*)Cout)[(size_t)row * 512 + col] = f2bf(v);
          else         ((float*)Cout)[(size_t)row * 512 + col] = v;
        }
      }
    }
  }
}

// ---------- fused pair kernel — 32x32x16 MFMA + FRAGMENT-ORDER LDS ----------
// One WG = one (i,j) pair x 128 batch rows. 512 threads (8 waves), 160 KB LDS.
// Quarter-outer XCD mapping; dbuf sA1, 1 barrier/K-step.
// sA1/sA2 stored in MFMA fragment-order: chunk = [k16][mt] of 1KB; lane l
// reads chunk_base + l*16 — fully contiguous ds_read_b128, conflict-free
// (round-12's row-major LDS was 4-way conflicted in 32-mode: 6.88M conflicts).
// k-loops unrolled x2 -> 16/8-MFMA clusters per load group.
__global__ __launch_bounds__(512, 2) void k_pair2(
    const unsigned short* __restrict__ UV,   // [8192][1024] bf16: U' | V'+ib1
    const unsigned short* __restrict__ W2q,  // 32-frag-order [32 k16][16 nt][512]
    const unsigned short* __restrict__ W3q,  // 32-frag-order [32 k16][8 nt][512]
    const float* __restrict__ b2,
    const float* __restrict__ b3,
    unsigned short* __restrict__ P){         // [240][131072] bf16 partials (permuted)
  __shared__ __align__(16) unsigned char sA1[2][128 * 128]; // 2 x 16 KB frag-order [4 k16][4 mt][1KB]
  __shared__ __align__(16) unsigned char sA2[128 * 1024];   // 128 KB frag-order [32 k16][4 mt][1KB]

  const int bid = blockIdx.x;
  const int xcd = bid & 7;
  const int cc  = bid >> 3;              // 0..119 within XCD
  const int q4  = cc / 30;               // quarter OUTER
  const int pl  = cc - q4 * 30;
  const int p   = xcd * 30 + pl;         // pair 0..239 (i-major per XCD)
  const int i   = p / 15;
  const int rj  = p - i * 15;
  const int j   = rj + (rj >= i ? 1 : 0);
  const int b0  = q4 * 128;

  const int t = threadIdx.x;
  const int w = t >> 6, l = t & 63;
  const int la = l & 31, h = l >> 5;
  const int n0w = w * 64;

  const unsigned short* Up = UV + (((size_t)(i * BB + b0)) << 10);
  const unsigned short* Vp = UV + (((size_t)(j * BB + b0)) << 10) + 512;

  const int sr = t >> 2, sk = (t & 3) << 4;
  const size_t srow = (size_t)sr << 10;
  // frag-order staging address: chunk = (local k16 = t&3)*4 + (sr>>5); slot = sr&31
  const unsigned fb = (unsigned)((((t & 3) << 2) + (sr >> 5)) << 10) + ((sr & 31) << 4);

  v8s u0, u1, v0, v1;

  auto ld_uv = [&](int kt){
    u0 = *(const v8s*)(Up + srow + kt + sk);
    u1 = *(const v8s*)(Up + srow + kt + sk + 8);
    v0 = *(const v8s*)(Vp + srow + kt + sk);
    v1 = *(const v8s*)(Vp + srow + kt + sk + 8);
  };
  auto build_a1 = [&](unsigned char* dst){
    float f0[8], f1[8];
#pragma unroll
    for (int e = 0; e < 8; e++){
      f0[e] = fmaxf(bf2f((unsigned short)u0[e]) + bf2f((unsigned short)v0[e]), 0.f);
      f1[e] = fmaxf(bf2f((unsigned short)u1[e]) + bf2f((unsigned short)v1[e]), 0.f);
    }
    v4u q0, q1;
    q0.x = cvt_pk(f0[0], f0[1]); q0.y = cvt_pk(f0[2], f0[3]);
    q0.z = cvt_pk(f0[4], f0[5]); q0.w = cvt_pk(f0[6], f0[7]);
    q1.x = cvt_pk(f1[0], f1[1]); q1.y = cvt_pk(f1[2], f1[3]);
    q1.z = cvt_pk(f1[4], f1[5]); q1.w = cvt_pk(f1[6], f1[7]);
    *(v4u*)(dst + fb) = q0;              // h16 = 0 (k = sk..sk+7)
    *(v4u*)(dst + fb + 512) = q1;        // h16 = 1 (k = sk+8..15)
  };

  // GEMM2: c2[nt][mt]; swapped mfma(w2, a1): D col(lane&31)=m, D rows(regs)=n.
  v16f c2[2][4];
#pragma unroll
  for (int nt = 0; nt < 2; nt++)
#pragma unroll
    for (int mt = 0; mt < 4; mt++)
#pragma unroll
      for (int e = 0; e < 16; e++) c2[nt][mt][e] = 0.f;

  // prologue: A1(0) into buf0; prime regs for A1(1)
  ld_uv(0);
  build_a1(&sA1[0][0]);
  ld_uv(64);

#pragma unroll
  for (int s = 0; s < 8; ++s){
    __syncthreads();                       // A1(s) visible; buf[(s+1)&1] free
    if (s < 7) build_a1(&sA1[(s + 1) & 1][0]);
    if (s < 6) ld_uv((s + 2) * 64);
    const unsigned char* bufc = &sA1[s & 1][0];
#pragma unroll
    for (int kp = 0; kp < 2; kp++){
      v8s w2f[2][2], a1f[2][4];
#pragma unroll
      for (int kki = 0; kki < 2; kki++){
        const int kkl = kp * 2 + kki;      // local k16 0..3
        const int K16 = s * 4 + kkl;       // global k16 0..31
#pragma unroll
        for (int nt = 0; nt < 2; nt++)
          w2f[kki][nt] = *(const v8s*)(W2q + (((size_t)((K16 << 4) + (w * 2 + nt))) << 9) + (l << 3));
#pragma unroll
        for (int mt = 0; mt < 4; mt++)
          a1f[kki][mt] = *(const v8s*)(bufc + (((kkl << 2) + mt) << 10) + (l << 4));
      }
      __builtin_amdgcn_s_setprio(1);
#pragma unroll
      for (int kki = 0; kki < 2; kki++)
#pragma unroll
        for (int nt = 0; nt < 2; nt++)
#pragma unroll
          for (int mt = 0; mt < 4; mt++)
            c2[nt][mt] = MFMA32(w2f[kki][nt], a1f[kki][mt], c2[nt][mt]);
      __builtin_amdgcn_s_setprio(0);
    }
  }

  // A2 = relu(c2 + b2) -> sA2 frag-order; n = n0w + nt*32 + 8q + 4h + r (reg=4q+r),
  // m = mt*32 + la. k2=n: chunk = (n>>4)*4 + mt ; slot = la + (q&1)*32 ; e = 4h+r.
#pragma unroll
  for (int nt = 0; nt < 2; nt++){
#pragma unroll
    for (int q = 0; q < 4; q++){
      const int nb = n0w + nt * 32 + 8 * q + 4 * h;
      const float4 bb = *(const float4*)(b2 + nb);
      const unsigned pa0 = (unsigned)((((w * 4 + nt * 2 + (q >> 1)) << 2)) << 10)
                         + ((la + ((q & 1) << 5)) << 4) + (h << 3);
#pragma unroll
      for (int mt = 0; mt < 4; mt++){
        uint2 u;
        u.x = cvt_pk(fmaxf(c2[nt][mt][4 * q + 0] + bb.x, 0.f), fmaxf(c2[nt][mt][4 * q + 1] + bb.y, 0.f));
        u.y = cvt_pk(fmaxf(c2[nt][mt][4 * q + 2] + bb.z, 0.f), fmaxf(c2[nt][mt][4 * q + 3] + bb.w, 0.f));
        *(uint2*)(sA2 + pa0 + (mt << 10)) = u;
      }
    }
  }
  __syncthreads();

  // GEMM3: barrier-free. wave (wm, wn): rows wm*64 (2 mt), cols wn*64 (2 nt).
  // un-swapped mfma(a2, w3): D col(lane&31)=n, D rows(regs)=m.
  const int wm = w & 1, wn = w >> 1;
  v16f c3[2][2];
#pragma unroll
  for (int mt = 0; mt < 2; mt++)
#pragma unroll
    for (int nt = 0; nt < 2; nt++)
#pragma unroll
      for (int e = 0; e < 16; e++) c3[mt][nt][e] = 0.f;

#pragma unroll
  for (int kk = 0; kk < 32; kk += 2){
    v8s a2f[2][2], w3f[2][2];
#pragma unroll
    for (int kki = 0; kki < 2; kki++){
      const int K16 = kk + kki;
#pragma unroll
      for (int nt = 0; nt < 2; nt++)
        w3f[kki][nt] = *(const v8s*)(W3q + (((size_t)((K16 << 3) + (wn * 2 + nt))) << 9) + (l << 3));
#pragma unroll
      for (int mt = 0; mt < 2; mt++)
        a2f[kki][mt] = *(const v8s*)(sA2 + (((K16 << 2) + (wm * 2 + mt)) << 10) + (l << 4));
    }
    __builtin_amdgcn_s_setprio(1);
#pragma unroll
    for (int kki = 0; kki < 2; kki++)
#pragma unroll
      for (int mt = 0; mt < 2; mt++)
#pragma unroll
        for (int nt = 0; nt < 2; nt++)
          c3[mt][nt] = MFMA32(a2f[kki][mt], w3f[kki][nt], c3[mt][nt]);
    __builtin_amdgcn_s_setprio(0);
  }

  // epilogue: relu(c3+b3) -> permuted P slab (same layout as round 12, verified).
  {
    const float b3v0 = b3[wn * 64 + la];
    const float b3v1 = b3[wn * 64 + 32 + la];
    unsigned short* pb = P + ((size_t)p << 17) + (la << 3) + (h << 2);
#pragma unroll
    for (int mt = 0; mt < 2; mt++){
      const int rg = (q4 * 2 + wm) * 2 + mt;
#pragma unroll
      for (int nt = 0; nt < 2; nt++){
        const int ng = wn * 2 + nt;
        const float bv = nt ? b3v1 : b3v0;
#pragma unroll
        for (int q = 0; q < 4; q++){
          const int BBi = (rg << 5) + (ng << 2) + q;
          v2u u;
          u.x = cvt_pk(fmaxf(c3[mt][nt][4 * q + 0] + bv, 0.f), fmaxf(c3[mt][nt][4 * q + 1] + bv, 0.f));
          u.y = cvt_pk(fmaxf(c3[mt][nt][4 * q + 2] + bv, 0.f), fmaxf(c3[mt][nt][4 * q + 3] + bv, 0.f));
          __builtin_nontemporal_store(u, (v2u*)(pb + ((size_t)BBi << 8)));
        }
      }
    }
  }
}

// ---------- slab reduction: out += sum_{15 slabs of i} P (decode permuted) ----------
__global__ __launch_bounds__(256) void k_reduce(const unsigned short* __restrict__ P,
                                                float* __restrict__ out){
  int idx = blockIdx.x * 256 + threadIdx.x;     // 262144 threads, one v8s each
  const int i  = idx >> 14;
  const int g8 = idx & 16383;                   // v8s unit within slab
  const unsigned short* pb = P + (((size_t)(i * 15)) << 17) + ((size_t)g8 << 3);
  float s[8] = {0.f,0.f,0.f,0.f,0.f,0.f,0.f,0.f};
#pragma unroll
  for (int sl = 0; sl < 15; sl++){
    v8s v = __builtin_nontemporal_load((const v8s*)(pb + ((size_t)sl << 17)));
#pragma unroll
    for (int e = 0; e < 8; e++) s[e] += bf2f((unsigned short)v[e]);
  }
  // decode: g8 = BB*32 + la ; BB = rg*32 + ng*4 + q ; elem e -> m-offset e
  const int la = g8 & 31, B = g8 >> 5;
  const int q = B & 3, ng = (B >> 2) & 7, rg = B >> 5;   // rg 0..15
  const int rowb = (i << 9) + rg * 32 + 8 * q;
  const int col  = ng * 32 + la;
  float* ob = out + ((size_t)rowb << 8) + col;
#pragma unroll
  for (int e = 0; e < 8; e++)
    ob[(size_t)(e << 8)] += s[e];
}

// ---------- host ----------

extern "C" void kernel_launch(void* const* d_in, const int* in_sizes, int n_in,
                              void* d_out, int out_size, void* d_ws, size_t ws_size,
                              hipStream_t stream){
  const float* objs = (const float*)d_in[0];
  const float* tW1  = (const float*)d_in[1];
  const float* tb1  = (const float*)d_in[2];
  const float* tW2  = (const float*)d_in[3];
  const float* tb2  = (const float*)d_in[4];
  const float* tW3  = (const float*)d_in[5];
  const float* tb3  = (const float*)d_in[6];
  const float* iW1  = (const float*)d_in[7];
  const float* ib1  = (const float*)d_in[8];
  const float* iW2  = (const float*)d_in[9];
  const float* ib2  = (const float*)d_in[10];
  const float* iW3  = (const float*)d_in[11];
  const float* ib3  = (const float*)d_in[12];

  char* ws = (char*)d_ws;
  size_t off = 0;
  unsigned short* objsb = (unsigned short*)(ws + off); off += (size_t)RR * DD * 2;        // 4 MB
  unsigned short* H1    = (unsigned short*)(ws + off); off += (size_t)RR * 512 * 2;       // 8 MB
  unsigned short* H2    = (unsigned short*)(ws + off); off += (size_t)RR * 512 * 2;       // 8 MB
  unsigned short* UVb   = (unsigned short*)(ws + off); off += (size_t)RR * 1024 * 2;      // 16 MB
  unsigned short* Wcat  = (unsigned short*)(ws + off); off += 1536 * 256 * 2;
  unsigned short* tW2t  = (unsigned short*)(ws + off); off += 512 * 512 * 2;
  unsigned short* tW3t  = (unsigned short*)(ws + off); off += 256 * 512 * 2;
  unsigned short* iW2q  = (unsigned short*)(ws + off); off += 512 * 512 * 2;
  unsigned short* iW3q  = (unsigned short*)(ws + off); off += 256 * 512 * 2;
  float*          bcat  = (float*)(ws + off);          off += 1536 * 4;
  unsigned short* P     = (unsigned short*)(ws + off); off += (size_t)240 * 512 * 256 * 2; // 60 MB
  (void)ws_size; (void)in_sizes; (void)n_in; (void)out_size;

  // prep (cast + transposes, one launch)
  k_prep<<<dim3(6662), dim3(256), 0, stream>>>(objs, tW1, tW2, tW3, iW1, iW2, iW3, tb1, ib1,
                                               objsb, Wcat, tW2t, tW3t, iW2q, iW3q, bcat);

  // merged H1 + UV GEMM (128x128 tiles, split epilogue)
  k_gemmB<256, true, false, true ><<<dim3(RR / 128, 12), dim3(256), 0, stream>>>(
      objsb, Wcat, bcat, H1, UVb);
  // H2 = relu(H1@tW2+tb2) (128x128 tiles)
  k_gemmB<512, true, true,  false><<<dim3(RR / 128, 4), dim3(256), 0, stream>>>(
      H1, tW2t, tb2, H2, nullptr);
  // T path: out = relu(H2@tW3+tb3) + objs (64x128 tiles, Nn=256)
  k_gemm<512, false, true, true, false><<<dim3(RR / 64, 2), dim3(256), 0, stream>>>(
      H2, tW3t, tb3, d_out, objs, nullptr, RR, DD);

  // fused pair interaction -> bf16 permuted partial slabs (nt stores)
  k_pair2<<<dim3(960), dim3(512), 0, stream>>>(UVb, iW2q, iW3q, ib2, ib3, P);

  // out += sum of 15 slabs per i
  k_reduce<<<dim3(1024), dim3(256), 0, stream>>>(P, (float*)d_out);
}

// Round 14
// 168.605 us; speedup vs baseline: 1.1808x; 1.0670x over previous
//
#include <hip/hip_runtime.h>

#define NN 16
#define BB 512
#define DD 256
#define RR (NN*BB)   // 8192

typedef __attribute__((ext_vector_type(8))) short v8s;
typedef __attribute__((ext_vector_type(4))) float v4f;
typedef __attribute__((ext_vector_type(4))) unsigned v4u;

#define MFMA16(a,b,c) __builtin_amdgcn_mfma_f32_16x16x32_bf16((a),(b),(c),0,0,0)

__device__ __forceinline__ unsigned short f2bf(float f){
  unsigned int x = __float_as_uint(f);
  x += 0x7fffu + ((x >> 16) & 1u);
  return (unsigned short)(x >> 16);
}
__device__ __forceinline__ float bf2f(unsigned short u){
  return __uint_as_float(((unsigned int)u) << 16);
}
// packed f32x2 -> bf16x2 (S0 -> low16, S1 -> high16), RTNE — same as f2bf
__device__ __forceinline__ unsigned cvt_pk(float lo, float hi){
  unsigned r;
  asm("v_cvt_pk_bf16_f32 %0, %1, %2" : "=v"(r) : "v"(lo), "v"(hi));
  return r;
}

// ---------- prep kernel (cast + weight transposes + concat, one launch) ----------
// iW2q/iW3q: 16x16x32 fragment-order (r11 proven):
//   d = ((k>>5)*NB + (n>>4))*512 + ((k>>3)&3)*128 + (n&15)*8 + (k&7)   (NB = N/16)
__global__ __launch_bounds__(256) void k_prep(
    const float* __restrict__ objs,
    const float* __restrict__ tW1, const float* __restrict__ tW2, const float* __restrict__ tW3,
    const float* __restrict__ iW1, const float* __restrict__ iW2, const float* __restrict__ iW3,
    const float* __restrict__ tb1, const float* __restrict__ ib1,
    unsigned short* __restrict__ objsb,
    unsigned short* __restrict__ Wcat, unsigned short* __restrict__ tW2t, unsigned short* __restrict__ tW3t,
    unsigned short* __restrict__ iW2q, unsigned short* __restrict__ iW3q,
    float* __restrict__ bcat){
  int idx = blockIdx.x * 256 + threadIdx.x;
  if (idx < 524288){                                   // objs cast, float4 path
    float4 v = ((const float4*)objs)[idx];
    ushort4 o;
    o.x = f2bf(v.x); o.y = f2bf(v.y); o.z = f2bf(v.z); o.w = f2bf(v.w);
    ((ushort4*)objsb)[idx] = o;
    return;
  }
  idx -= 524288;
  if (idx < 131072){                                   // Wcat rows 0..511 <- tW1 [256][512]
    int n = idx >> 8, k = idx & 255;
    Wcat[idx] = f2bf(tW1[k * 512 + n]);
    return;
  }
  idx -= 131072;
  if (idx < 262144){                                   // tW2t [512][512]
    int n = idx >> 9, k = idx & 511;
    tW2t[idx] = f2bf(tW2[k * 512 + n]);
    return;
  }
  idx -= 262144;
  if (idx < 131072){                                   // tW3t [256][512] <- tW3 [512][256]
    int n = idx >> 9, k = idx & 511;
    tW3t[idx] = f2bf(tW3[k * 256 + n]);
    return;
  }
  idx -= 131072;
  if (idx < 262144){                                   // iW2q (16-frag-order) <- iW2 [512][512]
    int n = idx >> 9, k = idx & 511;
    int d = (((k >> 5) * 32 + (n >> 4)) << 9) + (((k >> 3) & 3) << 7) + ((n & 15) << 3) + (k & 7);
    iW2q[d] = f2bf(iW2[k * 512 + n]);
    return;
  }
  idx -= 262144;
  if (idx < 131072){                                   // iW3q (16-frag-order) <- iW3 [512][256]
    int n = idx >> 9, k = idx & 511;
    int d = (((k >> 5) * 16 + (n >> 4)) << 9) + (((k >> 3) & 3) << 7) + ((n & 15) << 3) + (k & 7);
    iW3q[d] = f2bf(iW3[k * 256 + n]);
    return;
  }
  idx -= 131072;
  if (idx < 262144){                                   // Wcat rows 512..1535 <- iW1 split
    int r = idx >> 8, k = idx & 255;
    float v = (r < 512) ? iW1[k * 512 + r] : iW1[(k + 256) * 512 + (r - 512)];
    Wcat[(512 << 8) + idx] = f2bf(v);
    return;
  }
  idx -= 262144;
  if (idx < 1536)
    bcat[idx] = (idx < 512) ? tb1[idx] : ((idx < 1024) ? 0.f : ib1[idx - 1024]);
}

// ---------- phase-A GEMM, 64x128 tile (kept for the T GEMM) ----------
template<int KD, bool OUTBF16, bool RELU, bool ADDX, bool SPLIT>
__global__ __launch_bounds__(256) void k_gemm(const unsigned short* __restrict__ A,
                                              const unsigned short* __restrict__ Wt,
                                              const float* __restrict__ bias,
                                              void* __restrict__ Cout,
                                              const float* __restrict__ extra,
                                              void* __restrict__ Cout2,
                                              int M, int Nn){
  __shared__ __align__(16) unsigned char sA[64 * 128];
  __shared__ __align__(16) unsigned char sB[128 * 128];
  const int m0 = blockIdx.x * 64;
  const int n0 = blockIdx.y * 128;
  const int t = threadIdx.x;
  const int w = t >> 6, l = t & 63;
  const int l15 = l & 15, lq = l >> 4;
  const int rowh = (w & 1) * 32, colh = (w >> 1) * 64;

  v4f c[2][4];
#pragma unroll
  for (int r = 0; r < 2; r++)
#pragma unroll
    for (int q = 0; q < 4; q++) c[r][q] = (v4f){0.f, 0.f, 0.f, 0.f};

  for (int kt = 0; kt < KD; kt += 64){
    __syncthreads();
    {
      const int row = t >> 2, cq = (t & 3) * 16;
      const unsigned short* src = A + (size_t)(m0 + row) * KD + kt + cq;
      v8s a0 = *(const v8s*)(src);
      v8s a1 = *(const v8s*)(src + 8);
      const unsigned sw = (unsigned)((row & 7) << 4);
      *(v8s*)(sA + ((unsigned)((row << 7) + (cq << 1)) ^ sw)) = a0;
      *(v8s*)(sA + ((unsigned)((row << 7) + (cq << 1) + 16) ^ sw)) = a1;
    }
    {
      const int n = t & 127, kq = (t >> 7) * 32;
      const unsigned short* src = Wt + (size_t)(n0 + n) * KD + kt + kq;
      const unsigned base = (unsigned)((n << 7) + (kq << 1));
      const unsigned sw = (unsigned)((n & 7) << 4);
#pragma unroll
      for (int q = 0; q < 4; q++){
        v8s v = *(const v8s*)(src + q * 8);
        *(v8s*)(sB + ((base + q * 16) ^ sw)) = v;
      }
    }
    __syncthreads();
#pragma unroll
    for (int kb = 0; kb < 64; kb += 32){
      v8s af[2], bfr[4];
#pragma unroll
      for (int r = 0; r < 2; r++){
        const int row = rowh + r * 16 + l15;
        af[r] = *(const v8s*)(sA + ((unsigned)((row << 7) + ((kb + (lq << 3)) << 1)) ^ (unsigned)((row & 7) << 4)));
      }
#pragma unroll
      for (int q = 0; q < 4; q++){
        const int n = colh + q * 16 + l15;
        bfr[q] = *(const v8s*)(sB + ((unsigned)((n << 7) + ((kb + (lq << 3)) << 1)) ^ (unsigned)((n & 7) << 4)));
      }
#pragma unroll
      for (int r = 0; r < 2; r++)
#pragma unroll
        for (int q = 0; q < 4; q++)
          c[r][q] = MFMA16(af[r], bfr[q], c[r][q]);
    }
  }
#pragma unroll
  for (int r = 0; r < 2; r++){
#pragma unroll
    for (int q = 0; q < 4; q++){
      const int col = n0 + colh + q * 16 + l15;
      const float bv = bias ? bias[col] : 0.0f;
#pragma unroll
      for (int e = 0; e < 4; e++){
        const int row = m0 + rowh + r * 16 + (lq << 2) + e;
        float v = c[r][q][e] + bv;
        if (SPLIT){
          if (col < 512){
            ((unsigned short*)Cout)[(size_t)row * 512 + col] = f2bf(fmaxf(v, 0.0f));
          } else {
            ((unsigned short*)Cout2)[(size_t)row * 1024 + (col - 512)] = f2bf(v);
          }
        } else {
          if (RELU) v = fmaxf(v, 0.0f);
          if (ADDX) v += extra[(size_t)row * Nn + col];
          if (OUTBF16) ((unsigned short*)Cout)[(size_t)row * Nn + col] = f2bf(v);
          else         ((float*)Cout)[(size_t)row * Nn + col] = v;
        }
      }
    }
  }
}

// ---------- phase-A GEMM, 128x128 tile (merged H1/UV + H2) ----------
template<int KD, bool OUTBF16, bool RELU, bool SPLIT>
__global__ __launch_bounds__(256) void k_gemmB(const unsigned short* __restrict__ A,
                                               const unsigned short* __restrict__ Wt,
                                               const float* __restrict__ bias,
                                               void* __restrict__ Cout,
                                               void* __restrict__ Cout2){
  __shared__ __align__(16) unsigned char sA[128 * 128];  // [128 m][64 k]
  __shared__ __align__(16) unsigned char sB[128 * 128];  // [128 n][64 k]
  const int m0 = blockIdx.x * 128;
  const int n0 = blockIdx.y * 128;
  const int t = threadIdx.x;
  const int w = t >> 6, l = t & 63, l15 = l & 15, lq = l >> 4;
  const int wr = (w >> 1) * 64, wc = (w & 1) * 64;

  v4f c[4][4];
#pragma unroll
  for (int r = 0; r < 4; r++)
#pragma unroll
    for (int q = 0; q < 4; q++) c[r][q] = (v4f){0.f, 0.f, 0.f, 0.f};

  const int sr = t >> 1, sk = (t & 1) * 32;          // 2 threads/row, 32 k each
  const unsigned sbase = (unsigned)((sr << 7) + (sk << 1));
  const unsigned ssw = (unsigned)((sr & 7) << 4);

  for (int kt = 0; kt < KD; kt += 64){
    __syncthreads();
    { // stage A
      const unsigned short* src = A + (size_t)(m0 + sr) * KD + kt + sk;
      v8s a0 = *(const v8s*)(src);
      v8s a1 = *(const v8s*)(src + 8);
      v8s a2 = *(const v8s*)(src + 16);
      v8s a3 = *(const v8s*)(src + 24);
      *(v8s*)(sA + ((sbase +  0) ^ ssw)) = a0;
      *(v8s*)(sA + ((sbase + 16) ^ ssw)) = a1;
      *(v8s*)(sA + ((sbase + 32) ^ ssw)) = a2;
      *(v8s*)(sA + ((sbase + 48) ^ ssw)) = a3;
    }
    { // stage B
      const unsigned short* src = Wt + (size_t)(n0 + sr) * KD + kt + sk;
      v8s b0 = *(const v8s*)(src);
      v8s b1 = *(const v8s*)(src + 8);
      v8s b2 = *(const v8s*)(src + 16);
      v8s b3 = *(const v8s*)(src + 24);
      *(v8s*)(sB + ((sbase +  0) ^ ssw)) = b0;
      *(v8s*)(sB + ((sbase + 16) ^ ssw)) = b1;
      *(v8s*)(sB + ((sbase + 32) ^ ssw)) = b2;
      *(v8s*)(sB + ((sbase + 48) ^ ssw)) = b3;
    }
    __syncthreads();
#pragma unroll
    for (int kb = 0; kb < 64; kb += 32){
      v8s af[4], bfr[4];
#pragma unroll
      for (int r = 0; r < 4; r++){
        const int row = wr + r * 16 + l15;
        af[r] = *(const v8s*)(sA + ((unsigned)((row << 7) + ((kb + (lq << 3)) << 1)) ^ (unsigned)((row & 7) << 4)));
      }
#pragma unroll
      for (int q = 0; q < 4; q++){
        const int n = wc + q * 16 + l15;
        bfr[q] = *(const v8s*)(sB + ((unsigned)((n << 7) + ((kb + (lq << 3)) << 1)) ^ (unsigned)((n & 7) << 4)));
      }
#pragma unroll
      for (int r = 0; r < 4; r++)
#pragma unroll
        for (int q = 0; q < 4; q++)
          c[r][q] = MFMA16(af[r], bfr[q], c[r][q]);
    }
  }
#pragma unroll
  for (int r = 0; r < 4; r++){
#pragma unroll
    for (int q = 0; q < 4; q++){
      const int col = n0 + wc + q * 16 + l15;
      const float bv = bias ? bias[col] : 0.0f;
#pragma unroll
      for (int e = 0; e < 4; e++){
        const int row = m0 + wr + r * 16 + (lq << 2) + e;
        float v = c[r][q][e] + bv;
        if (SPLIT){
          if (col < 512){
            ((unsigned short*)Cout)[(size_t)row * 512 + col] = f2bf(fmaxf(v, 0.0f));
          } else {
            ((unsigned short*)Cout2)[(size_t)row * 1024 + (col - 512)] = f2bf(v);
          }
        } else {
          if (RELU) v = fmaxf(v, 0.0f);
          if (OUTBF16) ((unsigned short*)Cout)[(size_t)row * 512 + col] = f2bf(v);
          else         ((float*)Cout)[(size_t)row * 512 + col] = v;
        }
      }
    }
  }
}

// ---------- fused pair kernel — 16x16x32 MFMA (r11) + FRAGMENT-ORDER LDS ----------
// One WG = one (i,j) pair x 128 batch rows. 512 threads (8 waves), 160 KB LDS.
// Quarter-outer XCD mapping; dbuf sA1, 1 barrier/K-step.
// sA1: [2 k32][8 mf][1KB] frag-order; sA2: [16 k32][8 mt][1KB] frag-order.
// All fragment reads = chunk_base + l*16 (contiguous, conflict-free, no addr math).
// A1 element (m,k): chunk=(k>>5)*8+(m>>4), slot=(m&15)+((k>>3)&3)*16, e=k&7.
__global__ __launch_bounds__(512, 2) void k_pair2(
    const unsigned short* __restrict__ UV,   // [8192][1024] bf16: U' | V'+ib1
    const unsigned short* __restrict__ W2q,  // 16-frag-order [16 k32][32 nb][512]
    const unsigned short* __restrict__ W3q,  // 16-frag-order [16 k32][16 nb][512]
    const float* __restrict__ b2,
    const float* __restrict__ b3,
    unsigned short* __restrict__ P){         // [240][131072] bf16 partials (permuted)
  __shared__ __align__(16) unsigned char sA1[2][16384];  // 2 x 16 KB frag-order
  __shared__ __align__(16) unsigned char sA2[131072];    // 128 KB frag-order

  const int bid = blockIdx.x;
  const int xcd = bid & 7;
  const int cc  = bid >> 3;              // 0..119 within XCD
  const int q4  = cc / 30;               // quarter OUTER
  const int pl  = cc - q4 * 30;
  const int p   = xcd * 30 + pl;         // pair 0..239 (i-major per XCD)
  const int i   = p / 15;
  const int rj  = p - i * 15;
  const int j   = rj + (rj >= i ? 1 : 0);
  const int b0  = q4 * 128;

  const int t = threadIdx.x;
  const int w = t >> 6, l = t & 63, l15 = l & 15, lq = l >> 4;
  const int n0w = w * 64;

  const unsigned short* Up = UV + (((size_t)(i * BB + b0)) << 10);
  const unsigned short* Vp = UV + (((size_t)(j * BB + b0)) << 10) + 512;

  const int sr = t >> 2, sk = (t & 3) << 4;
  const size_t srow = (size_t)sr << 10;
  // frag-order staging address: chunk=(sk>>5)*8+(sr>>4); slot=(sr&15)+((sk>>3)&3)*16
  const unsigned fb0 = (unsigned)(((((sk >> 5) << 3) + (sr >> 4)) << 10)
                     + (((sr & 15) + (((sk >> 3) & 3) << 4)) << 4));

  // fragment-order weight bases: per-lane constant offset, contiguous per instr
  const unsigned short* W2l = W2q + ((size_t)(w * 4) << 9) + (lq << 7) + (l15 << 3);
  const unsigned short* W3l = W3q + (lq << 7) + (l15 << 3);

  v8s u0, u1, v0, v1;

  auto ld_uv = [&](int kt){
    u0 = *(const v8s*)(Up + srow + kt + sk);
    u1 = *(const v8s*)(Up + srow + kt + sk + 8);
    v0 = *(const v8s*)(Vp + srow + kt + sk);
    v1 = *(const v8s*)(Vp + srow + kt + sk + 8);
  };
  auto build_a1 = [&](unsigned char* dst){
    float f0[8], f1[8];
#pragma unroll
    for (int e = 0; e < 8; e++){
      f0[e] = fmaxf(bf2f((unsigned short)u0[e]) + bf2f((unsigned short)v0[e]), 0.f);
      f1[e] = fmaxf(bf2f((unsigned short)u1[e]) + bf2f((unsigned short)v1[e]), 0.f);
    }
    v4u q0, q1;
    q0.x = cvt_pk(f0[0], f0[1]); q0.y = cvt_pk(f0[2], f0[3]);
    q0.z = cvt_pk(f0[4], f0[5]); q0.w = cvt_pk(f0[6], f0[7]);
    q1.x = cvt_pk(f1[0], f1[1]); q1.y = cvt_pk(f1[2], f1[3]);
    q1.z = cvt_pk(f1[4], f1[5]); q1.w = cvt_pk(f1[6], f1[7]);
    *(v4u*)(dst + fb0) = q0;             // k = sk..sk+7
    *(v4u*)(dst + fb0 + 256) = q1;       // k = sk+8..sk+15 (slot+16)
  };

  v4f c2[4][8];
#pragma unroll
  for (int nf = 0; nf < 4; nf++)
#pragma unroll
    for (int mf = 0; mf < 8; mf++) c2[nf][mf] = (v4f){0.f, 0.f, 0.f, 0.f};

  // prologue: A1(0) into buf0; prime regs for A1(1)
  ld_uv(0);
  build_a1(&sA1[0][0]);
  ld_uv(64);

#pragma unroll
  for (int s = 0; s < 8; ++s){
    __syncthreads();                       // A1(s) visible; buf[(s+1)&1] free
    if (s < 7) build_a1(&sA1[(s + 1) & 1][0]);
    if (s < 6) ld_uv((s + 2) * 64);
    const int kt = s * 64;
    const unsigned char* bufc = &sA1[s & 1][0];
#pragma unroll
    for (int kbi = 0; kbi < 2; kbi++){
      v8s a1f[8], w2f[4];
      const unsigned short* W2s = W2l + ((size_t)(s * 2 + kbi) << 14);
#pragma unroll
      for (int nf = 0; nf < 4; nf++)
        w2f[nf] = *(const v8s*)(W2s + (nf << 9));
#pragma unroll
      for (int mf = 0; mf < 8; mf++)
        a1f[mf] = *(const v8s*)(bufc + (((kbi << 3) + mf) << 10) + (l << 4));
      __builtin_amdgcn_s_setprio(1);
#pragma unroll
      for (int nf = 0; nf < 4; nf++)
#pragma unroll
        for (int mf = 0; mf < 8; mf++)
          c2[nf][mf] = MFMA16(w2f[nf], a1f[mf], c2[nf][mf]);
      __builtin_amdgcn_s_setprio(0);
    }
    (void)kt;
  }

  // A2 = relu(c2 + b2) -> sA2 frag-order.
  // c2[nf][mf]: m = mf*16 + l15, n(=k2) = n0w + nf*16 + lq*4 + e.
  // chunk = (w*2 + (nf>>1))*8 + mf ; slot = l15 + ((nf*2 + (lq>>1))&3)*16 ;
  // byte off within slot = (lq&1)*8.
#pragma unroll
  for (int nf = 0; nf < 4; nf++){
    const float4 bb = *(const float4*)(b2 + n0w + nf * 16 + (lq << 2));
    const unsigned base = (unsigned)((((w * 2 + (nf >> 1)) << 3) << 10)
                        + ((l15 + (((nf * 2 + (lq >> 1)) & 3) << 4)) << 4)
                        + ((lq & 1) << 3));
#pragma unroll
    for (int mf = 0; mf < 8; mf++){
      v4f vv = c2[nf][mf];
      uint2 u;
      u.x = cvt_pk(fmaxf(vv[0] + bb.x, 0.f), fmaxf(vv[1] + bb.y, 0.f));
      u.y = cvt_pk(fmaxf(vv[2] + bb.z, 0.f), fmaxf(vv[3] + bb.w, 0.f));
      *(uint2*)(sA2 + base + (mf << 10)) = u;
    }
  }
  __syncthreads();

  // GEMM3: barrier-free. wave grid 2m x 4n (rows wm*64, cols wn*64).
  const int wm = w & 1, wn = w >> 1;
  const unsigned short* W3b = W3l + ((size_t)(wn * 4) << 9);
  v4f c3[4][4];
#pragma unroll
  for (int mf = 0; mf < 4; mf++)
#pragma unroll
    for (int nf = 0; nf < 4; nf++) c3[mf][nf] = (v4f){0.f, 0.f, 0.f, 0.f};

#pragma unroll 2
  for (int kb3 = 0; kb3 < 512; kb3 += 32){
    v8s a2f[4], w3f[4];
    const unsigned short* W3s = W3b + ((size_t)(kb3 >> 5) << 13);
#pragma unroll
    for (int nf = 0; nf < 4; nf++)
      w3f[nf] = *(const v8s*)(W3s + (nf << 9));
#pragma unroll
    for (int mf = 0; mf < 4; mf++)
      a2f[mf] = *(const v8s*)(sA2 + ((((kb3 >> 5) << 3) + (wm << 2) + mf) << 10) + (l << 4));
    __builtin_amdgcn_s_setprio(1);
#pragma unroll
    for (int mf = 0; mf < 4; mf++)
#pragma unroll
      for (int nf = 0; nf < 4; nf++)
        c3[mf][nf] = MFMA16(a2f[mf], w3f[nf], c3[mf][nf]);
    __builtin_amdgcn_s_setprio(0);
  }

  // epilogue: packed NON-TEMPORAL stores into permuted pair slab (r11 layout)
  {
    const float b3v0 = b3[wn * 64 +  0 + l15];
    const float b3v1 = b3[wn * 64 + 16 + l15];
    const float b3v2 = b3[wn * 64 + 32 + l15];
    const float b3v3 = b3[wn * 64 + 48 + l15];
    const int seg = q4 * 2 + wm;
    unsigned short* pb = P + ((size_t)p << 17) + ((size_t)l << 3);
#pragma unroll
    for (int mf = 0; mf < 4; mf++){
      v4u h0, h1;
      h0.x = cvt_pk(fmaxf(c3[mf][0][0] + b3v0, 0.f), fmaxf(c3[mf][0][1] + b3v0, 0.f));
      h0.y = cvt_pk(fmaxf(c3[mf][0][2] + b3v0, 0.f), fmaxf(c3[mf][0][3] + b3v0, 0.f));
      h0.z = cvt_pk(fmaxf(c3[mf][1][0] + b3v1, 0.f), fmaxf(c3[mf][1][1] + b3v1, 0.f));
      h0.w = cvt_pk(fmaxf(c3[mf][1][2] + b3v1, 0.f), fmaxf(c3[mf][1][3] + b3v1, 0.f));
      h1.x = cvt_pk(fmaxf(c3[mf][2][0] + b3v2, 0.f), fmaxf(c3[mf][2][1] + b3v2, 0.f));
      h1.y = cvt_pk(fmaxf(c3[mf][2][2] + b3v2, 0.f), fmaxf(c3[mf][2][3] + b3v2, 0.f));
      h1.z = cvt_pk(fmaxf(c3[mf][3][0] + b3v3, 0.f), fmaxf(c3[mf][3][1] + b3v3, 0.f));
      h1.w = cvt_pk(fmaxf(c3[mf][3][2] + b3v3, 0.f), fmaxf(c3[mf][3][3] + b3v3, 0.f));
      const int B = ((seg * 16 + wn * 4 + mf) << 1);
      __builtin_nontemporal_store(h0, (v4u*)(pb + ((size_t)B << 9)));
      __builtin_nontemporal_store(h1, (v4u*)(pb + ((size_t)(B + 1) << 9)));
    }
  }
}

// ---------- slab reduction: out += sum_{15 slabs of i} P (decode permuted, r11) ----------
__global__ __launch_bounds__(256) void k_reduce(const unsigned short* __restrict__ P,
                                                float* __restrict__ out){
  int idx = blockIdx.x * 256 + threadIdx.x;     // 262144 threads, 8 elems each
  const int i = idx >> 14;
  const int g = idx & 16383;                    // = B*64 + l
  const unsigned short* pb = P + (((size_t)(i * 15)) << 17) + ((size_t)g << 3);
  float s[8] = {0.f,0.f,0.f,0.f,0.f,0.f,0.f,0.f};
#pragma unroll
  for (int sl = 0; sl < 15; sl++){
    v8s v = __builtin_nontemporal_load((const v8s*)(pb + ((size_t)sl << 17)));
#pragma unroll
    for (int e = 0; e < 8; e++) s[e] += bf2f((unsigned short)v[e]);
  }
  // decode: B -> (seg, wn, mf, half); l -> (lq, l15); elem j -> (nf&1 = j>>2, e = j&3)
  const int l = g & 63, B = g >> 6;
  const int half = B & 1, mf = (B >> 1) & 3, wn = (B >> 3) & 3, seg = B >> 5;
  const int rowb = (i << 9) + seg * 64 + mf * 16 + ((l >> 4) << 2);
  const int colb = wn * 64 + half * 32 + (l & 15);
  float* ob = out + ((size_t)rowb << 8) + colb;
#pragma unroll
  for (int jj = 0; jj < 2; jj++)
#pragma unroll
    for (int e = 0; e < 4; e++)
      ob[(e << 8) + jj * 16] += s[jj * 4 + e];
}

// ---------- host ----------

extern "C" void kernel_launch(void* const* d_in, const int* in_sizes, int n_in,
                              void* d_out, int out_size, void* d_ws, size_t ws_size,
                              hipStream_t stream){
  const float* objs = (const float*)d_in[0];
  const float* tW1  = (const float*)d_in[1];
  const float* tb1  = (const float*)d_in[2];
  const float* tW2  = (const float*)d_in[3];
  const float* tb2  = (const float*)d_in[4];
  const float* tW3  = (const float*)d_in[5];
  const float* tb3  = (const float*)d_in[6];
  const float* iW1  = (const float*)d_in[7];
  const float* ib1  = (const float*)d_in[8];
  const float* iW2  = (const float*)d_in[9];
  const float* ib2  = (const float*)d_in[10];
  const float* iW3  = (const float*)d_in[11];
  const float* ib3  = (const float*)d_in[12];

  char* ws = (char*)d_ws;
  size_t off = 0;
  unsigned short* objsb = (unsigned short*)(ws + off); off += (size_t)RR * DD * 2;        // 4 MB
  unsigned short* H1    = (unsigned short*)(ws + off); off += (size_t)RR * 512 * 2;       // 8 MB
  unsigned short* H2    = (unsigned short*)(ws + off); off += (size_t)RR * 512 * 2;       // 8 MB
  unsigned short* UVb   = (unsigned short*)(ws + off); off += (size_t)RR * 1024 * 2;      // 16 MB
  unsigned short* Wcat  = (unsigned short*)(ws + off); off += 1536 * 256 * 2;
  unsigned short* tW2t  = (unsigned short*)(ws + off); off += 512 * 512 * 2;
  unsigned short* tW3t  = (unsigned short*)(ws + off); off += 256 * 512 * 2;
  unsigned short* iW2q  = (unsigned short*)(ws + off); off += 512 * 512 * 2;
  unsigned short* iW3q  = (unsigned short*)(ws + off); off += 256 * 512 * 2;
  float*          bcat  = (float*)(ws + off);          off += 1536 * 4;
  unsigned short* P     = (unsigned short*)(ws + off); off += (size_t)240 * 512 * 256 * 2; // 60 MB
  (void)ws_size; (void)in_sizes; (void)n_in; (void)out_size;

  // prep (cast + transposes, one launch)
  k_prep<<<dim3(6662), dim3(256), 0, stream>>>(objs, tW1, tW2, tW3, iW1, iW2, iW3, tb1, ib1,
                                               objsb, Wcat, tW2t, tW3t, iW2q, iW3q, bcat);

  // merged H1 + UV GEMM (128x128 tiles, split epilogue)
  k_gemmB<256, true, false, true ><<<dim3(RR / 128, 12), dim3(256), 0, stream>>>(
      objsb, Wcat, bcat, H1, UVb);
  // H2 = relu(H1@tW2+tb2) (128x128 tiles)
  k_gemmB<512, true, true,  false><<<dim3(RR / 128, 4), dim3(256), 0, stream>>>(
      H1, tW2t, tb2, H2, nullptr);
  // T path: out = relu(H2@tW3+tb3) + objs (64x128 tiles, Nn=256)
  k_gemm<512, false, true, true, false><<<dim3(RR / 64, 2), dim3(256), 0, stream>>>(
      H2, tW3t, tb3, d_out, objs, nullptr, RR, DD);

  // fused pair interaction -> bf16 permuted partial slabs (nt stores)
  k_pair2<<<dim3(960), dim3(512), 0, stream>>>(UVb, iW2q, iW3q, ib2, ib3, P);

  // out += sum of 15 slabs per i
  k_reduce<<<dim3(1024), dim3(256), 0, stream>>>(P, (float*)d_out);
}

// Round 15
// 167.313 us; speedup vs baseline: 1.1900x; 1.0077x over previous
//
#include <hip/hip_runtime.h>

#define NN 16
#define BB 512
#define DD 256
#define RR (NN*BB)   // 8192

typedef __attribute__((ext_vector_type(8))) short v8s;
typedef __attribute__((ext_vector_type(4))) float v4f;
typedef __attribute__((ext_vector_type(4))) unsigned v4u;

#define MFMA16(a,b,c) __builtin_amdgcn_mfma_f32_16x16x32_bf16((a),(b),(c),0,0,0)

__device__ __forceinline__ unsigned short f2bf(float f){
  unsigned int x = __float_as_uint(f);
  x += 0x7fffu + ((x >> 16) & 1u);
  return (unsigned short)(x >> 16);
}
__device__ __forceinline__ float bf2f(unsigned short u){
  return __uint_as_float(((unsigned int)u) << 16);
}
// packed f32x2 -> bf16x2 (S0 -> low16, S1 -> high16), RTNE — same as f2bf
__device__ __forceinline__ unsigned cvt_pk(float lo, float hi){
  unsigned r;
  asm("v_cvt_pk_bf16_f32 %0, %1, %2" : "=v"(r) : "v"(lo), "v"(hi));
  return r;
}

// ---------- prep kernel (cast + weight transposes + concat, one launch) ----------
// iW2q/iW3q: 16x16x32 fragment-order:
//   d = ((k>>5)*NB + (n>>4))*512 + ((k>>3)&3)*128 + (n&15)*8 + (k&7)   (NB = N/16)
__global__ __launch_bounds__(256) void k_prep(
    const float* __restrict__ objs,
    const float* __restrict__ tW1, const float* __restrict__ tW2, const float* __restrict__ tW3,
    const float* __restrict__ iW1, const float* __restrict__ iW2, const float* __restrict__ iW3,
    const float* __restrict__ tb1, const float* __restrict__ ib1,
    unsigned short* __restrict__ objsb,
    unsigned short* __restrict__ Wcat, unsigned short* __restrict__ tW2t, unsigned short* __restrict__ tW3t,
    unsigned short* __restrict__ iW2q, unsigned short* __restrict__ iW3q,
    float* __restrict__ bcat){
  int idx = blockIdx.x * 256 + threadIdx.x;
  if (idx < 524288){                                   // objs cast, float4 path
    float4 v = ((const float4*)objs)[idx];
    ushort4 o;
    o.x = f2bf(v.x); o.y = f2bf(v.y); o.z = f2bf(v.z); o.w = f2bf(v.w);
    ((ushort4*)objsb)[idx] = o;
    return;
  }
  idx -= 524288;
  if (idx < 131072){                                   // Wcat rows 0..511 <- tW1 [256][512]
    int n = idx >> 8, k = idx & 255;
    Wcat[idx] = f2bf(tW1[k * 512 + n]);
    return;
  }
  idx -= 131072;
  if (idx < 262144){                                   // tW2t [512][512]
    int n = idx >> 9, k = idx & 511;
    tW2t[idx] = f2bf(tW2[k * 512 + n]);
    return;
  }
  idx -= 262144;
  if (idx < 131072){                                   // tW3t [256][512] <- tW3 [512][256]
    int n = idx >> 9, k = idx & 511;
    tW3t[idx] = f2bf(tW3[k * 256 + n]);
    return;
  }
  idx -= 131072;
  if (idx < 262144){                                   // iW2q (16-frag-order) <- iW2 [512][512]
    int n = idx >> 9, k = idx & 511;
    int d = (((k >> 5) * 32 + (n >> 4)) << 9) + (((k >> 3) & 3) << 7) + ((n & 15) << 3) + (k & 7);
    iW2q[d] = f2bf(iW2[k * 512 + n]);
    return;
  }
  idx -= 262144;
  if (idx < 131072){                                   // iW3q (16-frag-order) <- iW3 [512][256]
    int n = idx >> 9, k = idx & 511;
    int d = (((k >> 5) * 16 + (n >> 4)) << 9) + (((k >> 3) & 3) << 7) + ((n & 15) << 3) + (k & 7);
    iW3q[d] = f2bf(iW3[k * 256 + n]);
    return;
  }
  idx -= 131072;
  if (idx < 262144){                                   // Wcat rows 512..1535 <- iW1 split
    int r = idx >> 8, k = idx & 255;
    float v = (r < 512) ? iW1[k * 512 + r] : iW1[(k + 256) * 512 + (r - 512)];
    Wcat[(512 << 8) + idx] = f2bf(v);
    return;
  }
  idx -= 262144;
  if (idx < 1536)
    bcat[idx] = (idx < 512) ? tb1[idx] : ((idx < 1024) ? 0.f : ib1[idx - 1024]);
}

// ---------- phase-A GEMM, 64x128 tile (kept for the T GEMM) ----------
template<int KD, bool OUTBF16, bool RELU, bool ADDX, bool SPLIT>
__global__ __launch_bounds__(256) void k_gemm(const unsigned short* __restrict__ A,
                                              const unsigned short* __restrict__ Wt,
                                              const float* __restrict__ bias,
                                              void* __restrict__ Cout,
                                              const float* __restrict__ extra,
                                              void* __restrict__ Cout2,
                                              int M, int Nn){
  __shared__ __align__(16) unsigned char sA[64 * 128];
  __shared__ __align__(16) unsigned char sB[128 * 128];
  const int m0 = blockIdx.x * 64;
  const int n0 = blockIdx.y * 128;
  const int t = threadIdx.x;
  const int w = t >> 6, l = t & 63;
  const int l15 = l & 15, lq = l >> 4;
  const int rowh = (w & 1) * 32, colh = (w >> 1) * 64;

  v4f c[2][4];
#pragma unroll
  for (int r = 0; r < 2; r++)
#pragma unroll
    for (int q = 0; q < 4; q++) c[r][q] = (v4f){0.f, 0.f, 0.f, 0.f};

  for (int kt = 0; kt < KD; kt += 64){
    __syncthreads();
    {
      const int row = t >> 2, cq = (t & 3) * 16;
      const unsigned short* src = A + (size_t)(m0 + row) * KD + kt + cq;
      v8s a0 = *(const v8s*)(src);
      v8s a1 = *(const v8s*)(src + 8);
      const unsigned sw = (unsigned)((row & 7) << 4);
      *(v8s*)(sA + ((unsigned)((row << 7) + (cq << 1)) ^ sw)) = a0;
      *(v8s*)(sA + ((unsigned)((row << 7) + (cq << 1) + 16) ^ sw)) = a1;
    }
    {
      const int n = t & 127, kq = (t >> 7) * 32;
      const unsigned short* src = Wt + (size_t)(n0 + n) * KD + kt + kq;
      const unsigned base = (unsigned)((n << 7) + (kq << 1));
      const unsigned sw = (unsigned)((n & 7) << 4);
#pragma unroll
      for (int q = 0; q < 4; q++){
        v8s v = *(const v8s*)(src + q * 8);
        *(v8s*)(sB + ((base + q * 16) ^ sw)) = v;
      }
    }
    __syncthreads();
#pragma unroll
    for (int kb = 0; kb < 64; kb += 32){
      v8s af[2], bfr[4];
#pragma unroll
      for (int r = 0; r < 2; r++){
        const int row = rowh + r * 16 + l15;
        af[r] = *(const v8s*)(sA + ((unsigned)((row << 7) + ((kb + (lq << 3)) << 1)) ^ (unsigned)((row & 7) << 4)));
      }
#pragma unroll
      for (int q = 0; q < 4; q++){
        const int n = colh + q * 16 + l15;
        bfr[q] = *(const v8s*)(sB + ((unsigned)((n << 7) + ((kb + (lq << 3)) << 1)) ^ (unsigned)((n & 7) << 4)));
      }
#pragma unroll
      for (int r = 0; r < 2; r++)
#pragma unroll
        for (int q = 0; q < 4; q++)
          c[r][q] = MFMA16(af[r], bfr[q], c[r][q]);
    }
  }
#pragma unroll
  for (int r = 0; r < 2; r++){
#pragma unroll
    for (int q = 0; q < 4; q++){
      const int col = n0 + colh + q * 16 + l15;
      const float bv = bias ? bias[col] : 0.0f;
#pragma unroll
      for (int e = 0; e < 4; e++){
        const int row = m0 + rowh + r * 16 + (lq << 2) + e;
        float v = c[r][q][e] + bv;
        if (SPLIT){
          if (col < 512){
            ((unsigned short*)Cout)[(size_t)row * 512 + col] = f2bf(fmaxf(v, 0.0f));
          } else {
            ((unsigned short*)Cout2)[(size_t)row * 1024 + (col - 512)] = f2bf(v);
          }
        } else {
          if (RELU) v = fmaxf(v, 0.0f);
          if (ADDX) v += extra[(size_t)row * Nn + col];
          if (OUTBF16) ((unsigned short*)Cout)[(size_t)row * Nn + col] = f2bf(v);
          else         ((float*)Cout)[(size_t)row * Nn + col] = v;
        }
      }
    }
  }
}

// ---------- phase-A GEMM, 128x128 tile (merged H1/UV + H2) ----------
template<int KD, bool OUTBF16, bool RELU, bool SPLIT>
__global__ __launch_bounds__(256) void k_gemmB(const unsigned short* __restrict__ A,
                                               const unsigned short* __restrict__ Wt,
                                               const float* __restrict__ bias,
                                               void* __restrict__ Cout,
                                               void* __restrict__ Cout2){
  __shared__ __align__(16) unsigned char sA[128 * 128];  // [128 m][64 k]
  __shared__ __align__(16) unsigned char sB[128 * 128];  // [128 n][64 k]
  const int m0 = blockIdx.x * 128;
  const int n0 = blockIdx.y * 128;
  const int t = threadIdx.x;
  const int w = t >> 6, l = t & 63, l15 = l & 15, lq = l >> 4;
  const int wr = (w >> 1) * 64, wc = (w & 1) * 64;

  v4f c[4][4];
#pragma unroll
  for (int r = 0; r < 4; r++)
#pragma unroll
    for (int q = 0; q < 4; q++) c[r][q] = (v4f){0.f, 0.f, 0.f, 0.f};

  const int sr = t >> 1, sk = (t & 1) * 32;          // 2 threads/row, 32 k each
  const unsigned sbase = (unsigned)((sr << 7) + (sk << 1));
  const unsigned ssw = (unsigned)((sr & 7) << 4);

  for (int kt = 0; kt < KD; kt += 64){
    __syncthreads();
    { // stage A
      const unsigned short* src = A + (size_t)(m0 + sr) * KD + kt + sk;
      v8s a0 = *(const v8s*)(src);
      v8s a1 = *(const v8s*)(src + 8);
      v8s a2 = *(const v8s*)(src + 16);
      v8s a3 = *(const v8s*)(src + 24);
      *(v8s*)(sA + ((sbase +  0) ^ ssw)) = a0;
      *(v8s*)(sA + ((sbase + 16) ^ ssw)) = a1;
      *(v8s*)(sA + ((sbase + 32) ^ ssw)) = a2;
      *(v8s*)(sA + ((sbase + 48) ^ ssw)) = a3;
    }
    { // stage B
      const unsigned short* src = Wt + (size_t)(n0 + sr) * KD + kt + sk;
      v8s b0 = *(const v8s*)(src);
      v8s b1 = *(const v8s*)(src + 8);
      v8s b2 = *(const v8s*)(src + 16);
      v8s b3 = *(const v8s*)(src + 24);
      *(v8s*)(sB + ((sbase +  0) ^ ssw)) = b0;
      *(v8s*)(sB + ((sbase + 16) ^ ssw)) = b1;
      *(v8s*)(sB + ((sbase + 32) ^ ssw)) = b2;
      *(v8s*)(sB + ((sbase + 48) ^ ssw)) = b3;
    }
    __syncthreads();
#pragma unroll
    for (int kb = 0; kb < 64; kb += 32){
      v8s af[4], bfr[4];
#pragma unroll
      for (int r = 0; r < 4; r++){
        const int row = wr + r * 16 + l15;
        af[r] = *(const v8s*)(sA + ((unsigned)((row << 7) + ((kb + (lq << 3)) << 1)) ^ (unsigned)((row & 7) << 4)));
      }
#pragma unroll
      for (int q = 0; q < 4; q++){
        const int n = wc + q * 16 + l15;
        bfr[q] = *(const v8s*)(sB + ((unsigned)((n << 7) + ((kb + (lq << 3)) << 1)) ^ (unsigned)((n & 7) << 4)));
      }
#pragma unroll
      for (int r = 0; r < 4; r++)
#pragma unroll
        for (int q = 0; q < 4; q++)
          c[r][q] = MFMA16(af[r], bfr[q], c[r][q]);
    }
  }
#pragma unroll
  for (int r = 0; r < 4; r++){
#pragma unroll
    for (int q = 0; q < 4; q++){
      const int col = n0 + wc + q * 16 + l15;
      const float bv = bias ? bias[col] : 0.0f;
#pragma unroll
      for (int e = 0; e < 4; e++){
        const int row = m0 + wr + r * 16 + (lq << 2) + e;
        float v = c[r][q][e] + bv;
        if (SPLIT){
          if (col < 512){
            ((unsigned short*)Cout)[(size_t)row * 512 + col] = f2bf(fmaxf(v, 0.0f));
          } else {
            ((unsigned short*)Cout2)[(size_t)row * 1024 + (col - 512)] = f2bf(v);
          }
        } else {
          if (RELU) v = fmaxf(v, 0.0f);
          if (OUTBF16) ((unsigned short*)Cout)[(size_t)row * 512 + col] = f2bf(v);
          else         ((float*)Cout)[(size_t)row * 512 + col] = v;
        }
      }
    }
  }
}

// ---------- fused pair kernel — 16x16x32 MFMA + frag-order LDS + mid-step build ----------
// One WG = one (i,j) pair x 128 batch rows. 512 threads (8 waves), 160 KB LDS.
// Quarter-outer XCD mapping; dbuf sA1, 1 barrier/K-step.
// CHANGE vs r14: build_a1(s+1) + ld_uv(s+2) moved BETWEEN kb0 and kb1 MFMA
// clusters — each step opens with loads+MFMA right after the barrier; the
// build VALU overlaps kb0's MFMA drain (compiler can't do this reorder: LDS
// alias analysis can't prove sA1[s&1] and sA1[(s+1)&1] disjoint).
__global__ __launch_bounds__(512, 2) void k_pair2(
    const unsigned short* __restrict__ UV,   // [8192][1024] bf16: U' | V'+ib1
    const unsigned short* __restrict__ W2q,  // 16-frag-order [16 k32][32 nb][512]
    const unsigned short* __restrict__ W3q,  // 16-frag-order [16 k32][16 nb][512]
    const float* __restrict__ b2,
    const float* __restrict__ b3,
    unsigned short* __restrict__ P){         // [240][131072] bf16 partials (permuted)
  __shared__ __align__(16) unsigned char sA1[2][16384];  // 2 x 16 KB frag-order
  __shared__ __align__(16) unsigned char sA2[131072];    // 128 KB frag-order

  const int bid = blockIdx.x;
  const int xcd = bid & 7;
  const int cc  = bid >> 3;              // 0..119 within XCD
  const int q4  = cc / 30;               // quarter OUTER
  const int pl  = cc - q4 * 30;
  const int p   = xcd * 30 + pl;         // pair 0..239 (i-major per XCD)
  const int i   = p / 15;
  const int rj  = p - i * 15;
  const int j   = rj + (rj >= i ? 1 : 0);
  const int b0  = q4 * 128;

  const int t = threadIdx.x;
  const int w = t >> 6, l = t & 63, l15 = l & 15, lq = l >> 4;
  const int n0w = w * 64;

  const unsigned short* Up = UV + (((size_t)(i * BB + b0)) << 10);
  const unsigned short* Vp = UV + (((size_t)(j * BB + b0)) << 10) + 512;

  const int sr = t >> 2, sk = (t & 3) << 4;
  const size_t srow = (size_t)sr << 10;
  // frag-order staging address: chunk=(sk>>5)*8+(sr>>4); slot=(sr&15)+((sk>>3)&3)*16
  const unsigned fb0 = (unsigned)(((((sk >> 5) << 3) + (sr >> 4)) << 10)
                     + (((sr & 15) + (((sk >> 3) & 3) << 4)) << 4));

  // fragment-order weight bases: per-lane constant offset, contiguous per instr
  const unsigned short* W2l = W2q + ((size_t)(w * 4) << 9) + (lq << 7) + (l15 << 3);
  const unsigned short* W3l = W3q + (lq << 7) + (l15 << 3);

  v8s u0, u1, v0, v1;

  auto ld_uv = [&](int kt){
    u0 = *(const v8s*)(Up + srow + kt + sk);
    u1 = *(const v8s*)(Up + srow + kt + sk + 8);
    v0 = *(const v8s*)(Vp + srow + kt + sk);
    v1 = *(const v8s*)(Vp + srow + kt + sk + 8);
  };
  auto build_a1 = [&](unsigned char* dst){
    float f0[8], f1[8];
#pragma unroll
    for (int e = 0; e < 8; e++){
      f0[e] = fmaxf(bf2f((unsigned short)u0[e]) + bf2f((unsigned short)v0[e]), 0.f);
      f1[e] = fmaxf(bf2f((unsigned short)u1[e]) + bf2f((unsigned short)v1[e]), 0.f);
    }
    v4u q0, q1;
    q0.x = cvt_pk(f0[0], f0[1]); q0.y = cvt_pk(f0[2], f0[3]);
    q0.z = cvt_pk(f0[4], f0[5]); q0.w = cvt_pk(f0[6], f0[7]);
    q1.x = cvt_pk(f1[0], f1[1]); q1.y = cvt_pk(f1[2], f1[3]);
    q1.z = cvt_pk(f1[4], f1[5]); q1.w = cvt_pk(f1[6], f1[7]);
    *(v4u*)(dst + fb0) = q0;             // k = sk..sk+7
    *(v4u*)(dst + fb0 + 256) = q1;       // k = sk+8..sk+15 (slot+16)
  };

  v4f c2[4][8];
#pragma unroll
  for (int nf = 0; nf < 4; nf++)
#pragma unroll
    for (int mf = 0; mf < 8; mf++) c2[nf][mf] = (v4f){0.f, 0.f, 0.f, 0.f};

  // prologue: A1(0) into buf0; prime regs for A1(1)
  ld_uv(0);
  build_a1(&sA1[0][0]);
  ld_uv(64);

#pragma unroll
  for (int s = 0; s < 8; ++s){
    __syncthreads();                       // A1(s) visible; buf[(s+1)&1] free
    const unsigned char* bufc = &sA1[s & 1][0];
    { // kb0: loads + MFMA immediately after barrier
      v8s a1f[8], w2f[4];
      const unsigned short* W2s = W2l + ((size_t)(s * 2) << 14);
#pragma unroll
      for (int nf = 0; nf < 4; nf++)
        w2f[nf] = *(const v8s*)(W2s + (nf << 9));
#pragma unroll
      for (int mf = 0; mf < 8; mf++)
        a1f[mf] = *(const v8s*)(bufc + (mf << 10) + (l << 4));
      __builtin_amdgcn_s_setprio(1);
#pragma unroll
      for (int nf = 0; nf < 4; nf++)
#pragma unroll
        for (int mf = 0; mf < 8; mf++)
          c2[nf][mf] = MFMA16(w2f[nf], a1f[mf], c2[nf][mf]);
      __builtin_amdgcn_s_setprio(0);
    }
    // mid-step: build next A1 tile + issue next UV loads (overlaps kb0 MFMA drain)
    if (s < 7) build_a1(&sA1[(s + 1) & 1][0]);
    if (s < 6) ld_uv((s + 2) * 64);
    { // kb1
      v8s a1f[8], w2f[4];
      const unsigned short* W2s = W2l + ((size_t)(s * 2 + 1) << 14);
#pragma unroll
      for (int nf = 0; nf < 4; nf++)
        w2f[nf] = *(const v8s*)(W2s + (nf << 9));
#pragma unroll
      for (int mf = 0; mf < 8; mf++)
        a1f[mf] = *(const v8s*)(bufc + ((8 + mf) << 10) + (l << 4));
      __builtin_amdgcn_s_setprio(1);
#pragma unroll
      for (int nf = 0; nf < 4; nf++)
#pragma unroll
        for (int mf = 0; mf < 8; mf++)
          c2[nf][mf] = MFMA16(w2f[nf], a1f[mf], c2[nf][mf]);
      __builtin_amdgcn_s_setprio(0);
    }
  }

  // A2 = relu(c2 + b2) -> sA2 frag-order.
  // c2[nf][mf]: m = mf*16 + l15, n(=k2) = n0w + nf*16 + lq*4 + e.
  // chunk = (w*2 + (nf>>1))*8 + mf ; slot = l15 + ((nf*2 + (lq>>1))&3)*16 ;
  // byte off within slot = (lq&1)*8.
#pragma unroll
  for (int nf = 0; nf < 4; nf++){
    const float4 bb = *(const float4*)(b2 + n0w + nf * 16 + (lq << 2));
    const unsigned base = (unsigned)((((w * 2 + (nf >> 1)) << 3) << 10)
                        + ((l15 + (((nf * 2 + (lq >> 1)) & 3) << 4)) << 4)
                        + ((lq & 1) << 3));
#pragma unroll
    for (int mf = 0; mf < 8; mf++){
      v4f vv = c2[nf][mf];
      uint2 u;
      u.x = cvt_pk(fmaxf(vv[0] + bb.x, 0.f), fmaxf(vv[1] + bb.y, 0.f));
      u.y = cvt_pk(fmaxf(vv[2] + bb.z, 0.f), fmaxf(vv[3] + bb.w, 0.f));
      *(uint2*)(sA2 + base + (mf << 10)) = u;
    }
  }
  __syncthreads();

  // GEMM3: barrier-free. wave grid 2m x 4n (rows wm*64, cols wn*64).
  const int wm = w & 1, wn = w >> 1;
  const unsigned short* W3b = W3l + ((size_t)(wn * 4) << 9);
  v4f c3[4][4];
#pragma unroll
  for (int mf = 0; mf < 4; mf++)
#pragma unroll
    for (int nf = 0; nf < 4; nf++) c3[mf][nf] = (v4f){0.f, 0.f, 0.f, 0.f};

#pragma unroll 2
  for (int kb3 = 0; kb3 < 512; kb3 += 32){
    v8s a2f[4], w3f[4];
    const unsigned short* W3s = W3b + ((size_t)(kb3 >> 5) << 13);
#pragma unroll
    for (int nf = 0; nf < 4; nf++)
      w3f[nf] = *(const v8s*)(W3s + (nf << 9));
#pragma unroll
    for (int mf = 0; mf < 4; mf++)
      a2f[mf] = *(const v8s*)(sA2 + ((((kb3 >> 5) << 3) + (wm << 2) + mf) << 10) + (l << 4));
    __builtin_amdgcn_s_setprio(1);
#pragma unroll
    for (int mf = 0; mf < 4; mf++)
#pragma unroll
      for (int nf = 0; nf < 4; nf++)
        c3[mf][nf] = MFMA16(a2f[mf], w3f[nf], c3[mf][nf]);
    __builtin_amdgcn_s_setprio(0);
  }

  // epilogue: packed NON-TEMPORAL stores into permuted pair slab
  {
    const float b3v0 = b3[wn * 64 +  0 + l15];
    const float b3v1 = b3[wn * 64 + 16 + l15];
    const float b3v2 = b3[wn * 64 + 32 + l15];
    const float b3v3 = b3[wn * 64 + 48 + l15];
    const int seg = q4 * 2 + wm;
    unsigned short* pb = P + ((size_t)p << 17) + ((size_t)l << 3);
#pragma unroll
    for (int mf = 0; mf < 4; mf++){
      v4u h0, h1;
      h0.x = cvt_pk(fmaxf(c3[mf][0][0] + b3v0, 0.f), fmaxf(c3[mf][0][1] + b3v0, 0.f));
      h0.y = cvt_pk(fmaxf(c3[mf][0][2] + b3v0, 0.f), fmaxf(c3[mf][0][3] + b3v0, 0.f));
      h0.z = cvt_pk(fmaxf(c3[mf][1][0] + b3v1, 0.f), fmaxf(c3[mf][1][1] + b3v1, 0.f));
      h0.w = cvt_pk(fmaxf(c3[mf][1][2] + b3v1, 0.f), fmaxf(c3[mf][1][3] + b3v1, 0.f));
      h1.x = cvt_pk(fmaxf(c3[mf][2][0] + b3v2, 0.f), fmaxf(c3[mf][2][1] + b3v2, 0.f));
      h1.y = cvt_pk(fmaxf(c3[mf][2][2] + b3v2, 0.f), fmaxf(c3[mf][2][3] + b3v2, 0.f));
      h1.z = cvt_pk(fmaxf(c3[mf][3][0] + b3v3, 0.f), fmaxf(c3[mf][3][1] + b3v3, 0.f));
      h1.w = cvt_pk(fmaxf(c3[mf][3][2] + b3v3, 0.f), fmaxf(c3[mf][3][3] + b3v3, 0.f));
      const int B = ((seg * 16 + wn * 4 + mf) << 1);
      __builtin_nontemporal_store(h0, (v4u*)(pb + ((size_t)B << 9)));
      __builtin_nontemporal_store(h1, (v4u*)(pb + ((size_t)(B + 1) << 9)));
    }
  }
}

// ---------- slab reduction: out += sum_{15 slabs of i} P (decode permuted) ----------
__global__ __launch_bounds__(256) void k_reduce(const unsigned short* __restrict__ P,
                                                float* __restrict__ out){
  int idx = blockIdx.x * 256 + threadIdx.x;     // 262144 threads, 8 elems each
  const int i = idx >> 14;
  const int g = idx & 16383;                    // = B*64 + l
  const unsigned short* pb = P + (((size_t)(i * 15)) << 17) + ((size_t)g << 3);
  float s[8] = {0.f,0.f,0.f,0.f,0.f,0.f,0.f,0.f};
#pragma unroll
  for (int sl = 0; sl < 15; sl++){
    v8s v = __builtin_nontemporal_load((const v8s*)(pb + ((size_t)sl << 17)));
#pragma unroll
    for (int e = 0; e < 8; e++) s[e] += bf2f((unsigned short)v[e]);
  }
  // decode: B -> (seg, wn, mf, half); l -> (lq, l15); elem j -> (nf&1 = j>>2, e = j&3)
  const int l = g & 63, B = g >> 6;
  const int half = B & 1, mf = (B >> 1) & 3, wn = (B >> 3) & 3, seg = B >> 5;
  const int rowb = (i << 9) + seg * 64 + mf * 16 + ((l >> 4) << 2);
  const int colb = wn * 64 + half * 32 + (l & 15);
  float* ob = out + ((size_t)rowb << 8) + colb;
#pragma unroll
  for (int jj = 0; jj < 2; jj++)
#pragma unroll
    for (int e = 0; e < 4; e++)
      ob[(e << 8) + jj * 16] += s[jj * 4 + e];
}

// ---------- host ----------

extern "C" void kernel_launch(void* const* d_in, const int* in_sizes, int n_in,
                              void* d_out, int out_size, void* d_ws, size_t ws_size,
                              hipStream_t stream){
  const float* objs = (const float*)d_in[0];
  const float* tW1  = (const float*)d_in[1];
  const float* tb1  = (const float*)d_in[2];
  const float* tW2  = (const float*)d_in[3];
  const float* tb2  = (const float*)d_in[4];
  const float* tW3  = (const float*)d_in[5];
  const float* tb3  = (const float*)d_in[6];
  const float* iW1  = (const float*)d_in[7];
  const float* ib1  = (const float*)d_in[8];
  const float* iW2  = (const float*)d_in[9];
  const float* ib2  = (const float*)d_in[10];
  const float* iW3  = (const float*)d_in[11];
  const float* ib3  = (const float*)d_in[12];

  char* ws = (char*)d_ws;
  size_t off = 0;
  unsigned short* objsb = (unsigned short*)(ws + off); off += (size_t)RR * DD * 2;        // 4 MB
  unsigned short* H1    = (unsigned short*)(ws + off); off += (size_t)RR * 512 * 2;       // 8 MB
  unsigned short* H2    = (unsigned short*)(ws + off); off += (size_t)RR * 512 * 2;       // 8 MB
  unsigned short* UVb   = (unsigned short*)(ws + off); off += (size_t)RR * 1024 * 2;      // 16 MB
  unsigned short* Wcat  = (unsigned short*)(ws + off); off += 1536 * 256 * 2;
  unsigned short* tW2t  = (unsigned short*)(ws + off); off += 512 * 512 * 2;
  unsigned short* tW3t  = (unsigned short*)(ws + off); off += 256 * 512 * 2;
  unsigned short* iW2q  = (unsigned short*)(ws + off); off += 512 * 512 * 2;
  unsigned short* iW3q  = (unsigned short*)(ws + off); off += 256 * 512 * 2;
  float*          bcat  = (float*)(ws + off);          off += 1536 * 4;
  unsigned short* P     = (unsigned short*)(ws + off); off += (size_t)240 * 512 * 256 * 2; // 60 MB
  (void)ws_size; (void)in_sizes; (void)n_in; (void)out_size;

  // prep (cast + transposes, one launch)
  k_prep<<<dim3(6662), dim3(256), 0, stream>>>(objs, tW1, tW2, tW3, iW1, iW2, iW3, tb1, ib1,
                                               objsb, Wcat, tW2t, tW3t, iW2q, iW3q, bcat);

  // merged H1 + UV GEMM (128x128 tiles, split epilogue)
  k_gemmB<256, true, false, true ><<<dim3(RR / 128, 12), dim3(256), 0, stream>>>(
      objsb, Wcat, bcat, H1, UVb);
  // H2 = relu(H1@tW2+tb2) (128x128 tiles)
  k_gemmB<512, true, true,  false><<<dim3(RR / 128, 4), dim3(256), 0, stream>>>(
      H1, tW2t, tb2, H2, nullptr);
  // T path: out = relu(H2@tW3+tb3) + objs (64x128 tiles, Nn=256)
  k_gemm<512, false, true, true, false><<<dim3(RR / 64, 2), dim3(256), 0, stream>>>(
      H2, tW3t, tb3, d_out, objs, nullptr, RR, DD);

  // fused pair interaction -> bf16 permuted partial slabs (nt stores)
  k_pair2<<<dim3(960), dim3(512), 0, stream>>>(UVb, iW2q, iW3q, ib2, ib3, P);

  // out += sum of 15 slabs per i
  k_reduce<<<dim3(1024), dim3(256), 0, stream>>>(P, (float*)d_out);
}